// Round 9
// baseline (173.820 us; speedup 1.0000x reference)
//
#include <hip/hip_runtime.h>
#include <cstdint>
#include <cstddef>

#define EPSC 1e-7f
#define EPS9 1e-9f
#define K4PI2 0.40528473456935108577f
#define NTOPK 10

__device__ __forceinline__ bool better(float v1, int i1, float v2, int i2) {
    return (v1 > v2) || ((v1 == v2) && (i1 < i2));
}

__device__ __forceinline__ bool mask_at(const unsigned char* mb, int i, int wide) {
    if (wide) return reinterpret_cast<const unsigned int*>(mb)[i] != 0u;
    return mb[i] != 0;
}

__device__ __forceinline__ unsigned long long shfl_xor_u64(unsigned long long v, int off) {
    int lo = __shfl_xor((int)(unsigned)(v & 0xFFFFFFFFull), off);
    int hi = __shfl_xor((int)(unsigned)(v >> 32), off);
    return ((unsigned long long)(unsigned)hi << 32) | (unsigned)lo;
}

__device__ __forceinline__ float ciou_clip(float x1a, float y1a, float x2a, float y2a,
                                           float w1h1, float atan1,
                                           float4 pb, float at2) {
    float w2 = pb.z - pb.x, h2 = pb.w - pb.y + EPSC;
    float iw = fmaxf(fminf(x2a, pb.z) - fmaxf(x1a, pb.x), 0.f);
    float ih = fmaxf(fminf(y2a, pb.w) - fmaxf(y1a, pb.y), 0.f);
    float inter = iw * ih;
    float uni = w1h1 + w2 * h2 - inter;
    float iou = inter / (uni + EPSC);
    float cw = fmaxf(x2a, pb.z) - fminf(x1a, pb.x);
    float ch = fmaxf(y2a, pb.w) - fminf(y1a, pb.y);
    float c2 = cw * cw + ch * ch + EPSC;
    float dx = pb.x + pb.z - x1a - x2a;
    float dy = pb.y + pb.w - y1a - y2a;
    float rho2 = (dx * dx + dy * dy) * 0.25f;
    float dat = at2 - atan1;
    float vv = K4PI2 * dat * dat;
    float aa = vv / (vv - iou + (1.f + EPSC));
    return fmaxf(iou - (rho2 / c2 + vv * aa), 0.f);
}

// K0: detect mask_gt memory layout. wide iff all n/4 leading words are {0,1,1.0f}
__global__ void k_detect(const unsigned char* __restrict__ mask, int n, int* __restrict__ mode) {
    __shared__ int bad;
    if (threadIdx.x == 0) bad = 0;
    __syncthreads();
    const unsigned int* w = reinterpret_cast<const unsigned int*>(mask);
    int nw = n >> 2;
    for (int i = threadIdx.x; i < nw; i += 256) {
        unsigned int v = w[i];
        if (v != 0u && v != 1u && v != 0x3f800000u) atomicOr(&bad, 1);
    }
    __syncthreads();
    if (threadIdx.x == 0) mode[0] = bad ? 0 : 1;
}

// K1 (anchor-major): one block per (b, 512-anchor chunk). GT boxes in LDS; per-thread
// 2 anchors (coalesced pb loads), dense 64-gt in-box bitmask, then per-set-bit:
// pooled-slot atomicAdd + exact metric + u64 key write. Requires M <= 64.
__global__ __launch_bounds__(256) void k_cand(
    const float* __restrict__ pd_scores, const float* __restrict__ pd_bboxes,
    const float* __restrict__ anc, const float* __restrict__ gt_labels,
    const float* __restrict__ gt_bboxes, const unsigned char* __restrict__ mask_gt,
    const int* __restrict__ mode,
    int* __restrict__ row_cnt, unsigned long long* __restrict__ pool,
    int* __restrict__ ovf,
    int A, int C, int M, int B, int CAPROW)
{
    __shared__ float4 s_gt[64];
    __shared__ float2 s_d[64];     // (w1h1, atan1)
    __shared__ int    s_l[64];

    int bid = blockIdx.x;
    int b = bid % B;               // XCD swizzle: same-b blocks share an XCD L2
    int chunk = bid / B;
    int tid = threadIdx.x;

    if (tid < M) {
        int row = b * M + tid;
        bool v = mask_at(mask_gt, row, mode[0]);
        float4 g;
        if (v) g = reinterpret_cast<const float4*>(gt_bboxes)[row];
        else   g = make_float4(3e38f, 3e38f, -3e38f, -3e38f);   // empty: no anchor passes
        s_gt[tid] = g;
        float w1 = g.z - g.x, h1 = g.w - g.y + EPSC;
        s_d[tid] = make_float2(w1 * h1, atanf(w1 / h1));
        s_l[tid] = v ? (int)gt_labels[row] : -1;
    }
    __syncthreads();

    const float2* an2 = reinterpret_cast<const float2*>(anc);
    const float4* pb4 = reinterpret_cast<const float4*>(pd_bboxes + (size_t)b * A * 4);
    const float*  ps  = pd_scores + (size_t)b * A * C;

    int a0 = chunk * 512 + tid;
    int a1 = a0 + 256;
    bool okA = a0 < A, okB = a1 < A;
    float2 apA = okA ? an2[a0] : make_float2(0.f, 0.f);
    float2 apB = okB ? an2[a1] : make_float2(0.f, 0.f);
    float4 pbA = okA ? pb4[a0] : make_float4(0.f, 0.f, 0.f, 0.f);
    float4 pbB = okB ? pb4[a1] : make_float4(0.f, 0.f, 0.f, 0.f);
    float atA = okA ? atanf((pbA.z - pbA.x) / (pbA.w - pbA.y + EPSC)) : 0.f;
    float atB = okB ? atanf((pbB.z - pbB.x) / (pbB.w - pbB.y + EPSC)) : 0.f;

    // dense branch-free in-box bitmasks over all gts
    unsigned long long mk0 = 0, mk1 = 0;
    for (int m = 0; m < M; ++m) {
        float4 g = s_gt[m];
        bool iA = okA & (apA.x - g.x > EPS9) & (apA.y - g.y > EPS9) &
                        (g.z - apA.x > EPS9) & (g.w - apA.y > EPS9);
        bool iB = okB & (apB.x - g.x > EPS9) & (apB.y - g.y > EPS9) &
                        (g.z - apB.x > EPS9) & (g.w - apB.y > EPS9);
        mk0 |= (unsigned long long)iA << m;
        mk1 |= (unsigned long long)iB << m;
    }

    auto emit = [&](int m, int a, const float4& pb, float at2) {
        int row = b * M + m;
        int slot = atomicAdd(&row_cnt[row], 1);
        if (slot < CAPROW) {
            float4 g = s_gt[m]; float2 d = s_d[m]; int lbl = s_l[m];
            float ovl = ciou_clip(g.x, g.y, g.z, g.w, d.x, d.y, pb, at2);
            float sc = (lbl >= 0) ? ps[(size_t)a * C + lbl] : 0.f;
            float o2 = ovl * ovl;
            float val = sqrtf(sc) * (o2 * o2 * o2);
            // key max-order == (val desc, idx asc); val>=0 so float bits are monotone
            pool[(size_t)row * CAPROW + slot] =
                ((unsigned long long)__float_as_uint(val) << 32) | (unsigned)(~(unsigned)a);
        } else {
            ovf[row] = 1;          // benign race (same value); exact fallback handles row
        }
    };
    while (mk0) { int m = __builtin_ctzll(mk0); mk0 &= mk0 - 1; emit(m, a0, pbA, atA); }
    while (mk1) { int m = __builtin_ctzll(mk1); mk1 &= mk1 - 1; emit(m, a1, pbB, atB); }
}

// K2: per (b,m) single-wave top-10 from pooled keys == lax.top_k (value desc, idx asc)
__global__ __launch_bounds__(64) void k_sel(
    const unsigned long long* __restrict__ pool, const int* __restrict__ row_cnt,
    const int* __restrict__ ovf, const unsigned char* __restrict__ mask_gt,
    const int* __restrict__ mode,
    const float* __restrict__ gt_bboxes, const float* __restrict__ anc,
    int* __restrict__ count, int* __restrict__ win_idx, float* __restrict__ win_al,
    int* __restrict__ win_fl,
    int A, int M, int CAPROW)
{
    int row = blockIdx.x;
    if (ovf[row]) return;                        // exact fallback kernel handles this row
    if (!mask_at(mask_gt, row, mode[0])) return; // win_fl pre-zeroed -> no claims
    int lane = threadIdx.x;
    int cnt = row_cnt[row];
    if (cnt > CAPROW) return;                    // paranoia (implies ovf)
    int b = row / M;
    size_t bA = (size_t)b * A;
    int base_o = row * NTOPK;

    // per-lane register top-10 (lossless: global top-10 subset of union of lane top-10s)
    const unsigned long long* rp = pool + (size_t)row * CAPROW;
    unsigned long long tv[NTOPK];
#pragma unroll
    for (int j = 0; j < NTOPK; ++j) tv[j] = 0;
    int pcnt = 0;
    for (int i = lane; i < cnt; i += 64) {
        unsigned long long kk = rp[i];
        pcnt += (kk >> 32) ? 1 : 0;              // val > 0
        if (kk > tv[NTOPK - 1]) {
            tv[NTOPK - 1] = kk;
#pragma unroll
            for (int j = NTOPK - 1; j > 0; --j)
                if (tv[j] > tv[j - 1]) { unsigned long long t = tv[j]; tv[j] = tv[j - 1]; tv[j - 1] = t; }
        }
    }
#pragma unroll
    for (int off = 32; off; off >>= 1) pcnt += __shfl_xor(pcnt, off);
    int p = pcnt;
    int rpos = p < NTOPK ? p : NTOPK;

    // 3a: positive rounds — register head + wave-max butterfly, winner pops
    for (int k = 0; k < rpos; ++k) {
        unsigned long long head = tv[0];
        unsigned long long best = head;
#pragma unroll
        for (int off = 32; off; off >>= 1) {
            unsigned long long o = shfl_xor_u64(best, off);
            if (o > best) best = o;
        }
        if (head == best && head != 0ull) {      // unique owner (keys unique by idx)
            int a = (int)(~(unsigned)(best & 0xFFFFFFFFull));
            int o = base_o + k;
            win_idx[o] = a;
            win_al[o]  = __uint_as_float((unsigned)(best >> 32));
            win_fl[o]  = 1;
            atomicAdd(&count[bA + a], 1);
#pragma unroll
            for (int j = 0; j < NTOPK - 1; ++j) tv[j] = tv[j + 1];
            tv[NTOPK - 1] = 0;
        }
    }

    // 3b (rare: p < 10): fill with smallest-index zero-val anchors; in-box zero-vals
    // (largest zero-keys, retained in tv) become real zero-metric claims.
    if (rpos < NTOPK) {
        float4 g = reinterpret_cast<const float4*>(gt_bboxes)[row];
        float x1a = g.x, y1a = g.y, x2a = g.z, y2a = g.w;
        const float2* an2 = reinterpret_cast<const float2*>(anc);
        int iters = (A + 63 - lane) / 64;
        int zp = 0;
        for (int k = rpos; k < NTOPK; ++k) {
            unsigned zprop = 0xFFFFFFFFu;        // next out-of-box anchor (padding, no claim)
            while (zp < iters) {
                int a = lane + zp * 64;
                float2 ap = an2[a];
                bool in = (ap.x - x1a > EPS9) & (ap.y - y1a > EPS9) &
                          (x2a - ap.x > EPS9) & (y2a - ap.y > EPS9);
                if (!in) { zprop = (unsigned)a; break; }
                ++zp;
            }
            unsigned cprop = 0xFFFFFFFFu;        // unconsumed in-box zero-val (regs)
#pragma unroll
            for (int j = 0; j < NTOPK; ++j) {
                unsigned long long kk = tv[j];
                if (kk != 0ull && kk < (1ull << 32)) {
                    unsigned idx2 = ~(unsigned)kk;
                    if (idx2 < cprop) cprop = idx2;
                }
            }
            unsigned prop = zprop < cprop ? zprop : cprop;
            unsigned bm_ = prop;
#pragma unroll
            for (int off = 32; off; off >>= 1) {
                unsigned o = (unsigned)__shfl_xor((int)bm_, off);
                if (o < bm_) bm_ = o;
            }
            if (bm_ != 0xFFFFFFFFu) {
                if (cprop == bm_ && cprop < zprop) {
                    int o = base_o + k;
                    win_idx[o] = (int)bm_; win_al[o] = 0.f; win_fl[o] = 1;
                    atomicAdd(&count[bA + bm_], 1);
                    unsigned long long wkk = (unsigned long long)(unsigned)(~bm_);
#pragma unroll
                    for (int j = 0; j < NTOPK; ++j) if (tv[j] == wkk) tv[j] = 0;
                } else if (zprop == bm_ && zprop < cprop) {
                    ++zp;
                }
            }
        }
    }
}

// K2fb: exact fallback (round-3 algorithm) for overflow rows (or M>64)
__global__ __launch_bounds__(256) void k_topk_fb(
    const float* __restrict__ pd_scores, const float* __restrict__ pd_bboxes,
    const float* __restrict__ anc, const float* __restrict__ gt_labels,
    const float* __restrict__ gt_bboxes, const unsigned char* __restrict__ mask_gt,
    const int* __restrict__ mode,
    const int* __restrict__ ovf,
    int* __restrict__ count, int* __restrict__ win_idx, float* __restrict__ win_al,
    int* __restrict__ win_fl,
    int A, int C, int M)
{
    int row = blockIdx.x;
    if (!ovf[row]) return;
    if (!mask_at(mask_gt, row, mode[0])) return;
    int b = row / M;
    int tid = threadIdx.x;

    float4 g = reinterpret_cast<const float4*>(gt_bboxes)[row];
    float x1a = g.x, y1a = g.y, x2a = g.z, y2a = g.w;
    float w1 = x2a - x1a, h1 = y2a - y1a + EPSC;
    float w1h1 = w1 * h1;
    float atan1 = atanf(w1 / h1);
    int lbl = (int)gt_labels[row];

    const float4* pb4 = reinterpret_cast<const float4*>(pd_bboxes + (size_t)b * A * 4);
    const float*  ps  = pd_scores + (size_t)b * A * C;
    const float2* an2 = reinterpret_cast<const float2*>(anc);

    float tv[NTOPK];
    int   ti[NTOPK], tfl[NTOPK];
#pragma unroll
    for (int j = 0; j < NTOPK; ++j) { tv[j] = -1.f; ti[j] = 0x7fffffff; tfl[j] = 0; }

    for (int a = tid; a < A; a += 256) {
        float2 ap = an2[a];
        bool in = (ap.x - x1a > EPS9) & (ap.y - y1a > EPS9) &
                  (x2a - ap.x > EPS9) & (y2a - ap.y > EPS9);
        float val = 0.f;
        if (in) {
            float4 pb = pb4[a];
            float w2 = pb.z - pb.x, h2 = pb.w - pb.y + EPSC;
            float ovl = ciou_clip(x1a, y1a, x2a, y2a, w1h1, atan1, pb, atanf(w2 / h2));
            float sc = (lbl >= 0) ? ps[(size_t)a * C + lbl] : 0.f;
            float o2 = ovl * ovl;
            val = sqrtf(sc) * (o2 * o2 * o2);
        }
        if (better(val, a, tv[NTOPK - 1], ti[NTOPK - 1])) {
            tv[NTOPK - 1] = val; ti[NTOPK - 1] = a; tfl[NTOPK - 1] = in ? 1 : 0;
#pragma unroll
            for (int j = NTOPK - 1; j > 0; --j) {
                if (better(tv[j], ti[j], tv[j - 1], ti[j - 1])) {
                    float fv = tv[j]; tv[j] = tv[j - 1]; tv[j - 1] = fv;
                    int   fi = ti[j]; ti[j] = ti[j - 1]; ti[j - 1] = fi;
                    int   ff = tfl[j]; tfl[j] = tfl[j - 1]; tfl[j - 1] = ff;
                }
            }
        }
    }

    __shared__ float swv[8];
    __shared__ int   swi[8];
    int lane = tid & 63, wid = tid >> 6;
    int base_o = row * NTOPK;

    for (int k = 0; k < NTOPK; ++k) {
        float bv = -2.f; int bi = 0x7fffffff;
#pragma unroll
        for (int j = 0; j < NTOPK; ++j)
            if (better(tv[j], ti[j], bv, bi)) { bv = tv[j]; bi = ti[j]; }
#pragma unroll
        for (int off = 32; off > 0; off >>= 1) {
            float ov = __shfl_xor(bv, off);
            int   oi = __shfl_xor(bi, off);
            if (better(ov, oi, bv, bi)) { bv = ov; bi = oi; }
        }
        if (lane == 0) { swv[wid] = bv; swi[wid] = bi; }
        __syncthreads();
        if (tid == 0) {
            float gv = swv[0]; int gi = swi[0];
            for (int w = 1; w < 4; ++w)
                if (better(swv[w], swi[w], gv, gi)) { gv = swv[w]; gi = swi[w]; }
            swv[7] = gv; swi[7] = gi;
        }
        __syncthreads();
        int gbi = swi[7];
#pragma unroll
        for (int j = 0; j < NTOPK; ++j) {
            if (ti[j] == gbi) {
                int o = base_o + k;
                win_idx[o] = gbi; win_al[o] = tv[j]; win_fl[o] = tfl[j];
                if (tfl[j]) atomicAdd(&count[(size_t)b * A + gbi], 1);
                tv[j] = -2.f; ti[j] = 0x7fffffff;
            }
        }
        __syncthreads();
    }
}

// K3: claim resolution + fused pos_al/pos_ov atomicMax (winner CIoU recomputed)
__global__ void k_resolve(
    const float* __restrict__ pd_scores, const float* __restrict__ pd_bboxes,
    const float* __restrict__ anc, const float* __restrict__ gt_labels,
    const float* __restrict__ gt_bboxes, const unsigned char* __restrict__ mask_gt,
    const int* __restrict__ mode,
    const int* __restrict__ count, const int* __restrict__ win_idx,
    const float* __restrict__ win_al, const int* __restrict__ win_fl,
    int* __restrict__ claim_m, float* __restrict__ claim_al,
    float* __restrict__ pos_al, float* __restrict__ pos_ov,
    int A, int C, int M, int total)
{
    int t = blockIdx.x * 256 + threadIdx.x;
    if (t >= total) return;
    int bm = t / NTOPK;
    int b = bm / M, m = bm % M;
    if (!win_fl[t]) return;
    int a = win_idx[t];
    size_t ba = (size_t)b * A + a;
    int cnt = count[ba];
    float al, ov; int mm_out;
    if (cnt == 1) {
        mm_out = m; al = win_al[t];
        float4 gg = reinterpret_cast<const float4*>(gt_bboxes)[b * M + m];
        float w1 = gg.z - gg.x, h1 = gg.w - gg.y + EPSC;
        float4 pb = reinterpret_cast<const float4*>(pd_bboxes)[ba];
        float w2 = pb.z - pb.x, h2p = pb.w - pb.y + EPSC;
        ov = ciou_clip(gg.x, gg.y, gg.z, gg.w, w1 * h1, atanf(w1 / h1), pb, atanf(w2 / h2p));
    } else {
        int wide = mode[0];
        float4 pb = reinterpret_cast<const float4*>(pd_bboxes)[ba];
        float2 ap = reinterpret_cast<const float2*>(anc)[a];
        float w2 = pb.z - pb.x, h2p = pb.w - pb.y + EPSC;
        float at2 = atanf(w2 / h2p);
        float best_ov = -1.f; int best_m = 0, best_valid = 0;
        for (int mm = 0; mm < M; ++mm) {
            float4 gg = reinterpret_cast<const float4*>(gt_bboxes)[b * M + mm];
            bool in = (ap.x - gg.x > EPS9) && (ap.y - gg.y > EPS9) &&
                      (gg.z - ap.x > EPS9) && (gg.w - ap.y > EPS9);
            bool valid = in && mask_at(mask_gt, b * M + mm, wide);
            float ovv = 0.f;
            if (valid) {
                float w1 = gg.z - gg.x, h1 = gg.w - gg.y + EPSC;
                ovv = ciou_clip(gg.x, gg.y, gg.z, gg.w, w1 * h1, atanf(w1 / h1), pb, at2);
            }
            if (ovv > best_ov) { best_ov = ovv; best_m = mm; best_valid = valid ? 1 : 0; }
        }
        int lb = (int)gt_labels[b * M + best_m];
        float sc = (best_valid && lb >= 0) ? pd_scores[ba * C + lb] : 0.f;
        float o2 = best_ov * best_ov;
        mm_out = best_m; al = sqrtf(sc) * (o2 * o2 * o2); ov = best_ov;
    }
    claim_m[ba]  = mm_out;
    claim_al[ba] = al;
    atomicMax((unsigned int*)&pos_al[b * M + mm_out], __float_as_uint(al));
    atomicMax((unsigned int*)&pos_ov[b * M + mm_out], __float_as_uint(ov));
}

// K4: fused finalize — per-anchor (bb, fg, nv, lb) then coalesced score writes
__global__ __launch_bounds__(256) void k_final(
    const int* __restrict__ count, const int* __restrict__ claim_m,
    const float* __restrict__ claim_al,
    const float* __restrict__ pos_al, const float* __restrict__ pos_ov,
    const float* __restrict__ gt_labels, const float* __restrict__ gt_bboxes,
    float* __restrict__ out_bb, float* __restrict__ out_ts, float* __restrict__ out_fg,
    int A, int M, int C4, int BA)
{
    __shared__ float s_nv[256];
    __shared__ int   s_lb[256];
    int base_ba = blockIdx.x * 256;
    int tid = threadIdx.x;
    int ba = base_ba + tid;
    if (ba < BA) {
        int b = ba / A;
        int cnt = count[ba];
        int m = claim_m[ba];                   // 0 for background (memset)
        float4 g = reinterpret_cast<const float4*>(gt_bboxes)[b * M + m];
        reinterpret_cast<float4*>(out_bb)[ba] = g;
        float nv = 0.f; int lb = -1;
        if (cnt > 0) {
            lb = max((int)gt_labels[b * M + m], 0);
            nv = claim_al[ba] * pos_ov[b * M + m] / (pos_al[b * M + m] + EPS9);
        }
        out_fg[ba] = (cnt > 0) ? 1.f : 0.f;
        s_nv[tid] = nv; s_lb[tid] = lb;
    } else { s_nv[tid] = 0.f; s_lb[tid] = -1; }
    __syncthreads();
    float4* ts4 = reinterpret_cast<float4*>(out_ts);
    size_t fbase = (size_t)base_ba * C4;
    for (int j = 0; j < C4; ++j) {
        int fl = j * 256 + tid;                // consecutive tid -> consecutive float4s
        int la = fl / C4;
        int ch = fl - la * C4;
        int ba2 = base_ba + la;
        if (ba2 < BA) {
            float nv = s_nv[la];
            int lb = s_lb[la];
            int c0 = ch * 4;
            float4 o;
            o.x = (c0     == lb) ? nv : 0.f;
            o.y = (c0 + 1 == lb) ? nv : 0.f;
            o.z = (c0 + 2 == lb) ? nv : 0.f;
            o.w = (c0 + 3 == lb) ? nv : 0.f;
            ts4[fbase + fl] = o;
        }
    }
}

extern "C" void kernel_launch(void* const* d_in, const int* in_sizes, int n_in,
                              void* d_out, int out_size, void* d_ws, size_t ws_size,
                              hipStream_t stream) {
    const float* pd_scores = (const float*)d_in[0];
    const float* pd_bboxes = (const float*)d_in[1];
    const float* anc       = (const float*)d_in[2];
    const float* gt_labels = (const float*)d_in[3];
    const float* gt_bboxes = (const float*)d_in[4];
    const unsigned char* mask_gt = (const unsigned char*)d_in[5];

    int A  = in_sizes[2] / 2;
    int BA = in_sizes[1] / 4;
    int B  = BA / A;
    int C  = in_sizes[0] / BA;
    int M  = in_sizes[3] / B;
    int BM = B * M;

    // workspace carve (256B-aligned bumps; zeroed span is contiguous); pool gets leftover
    char* w = (char*)d_ws;
    auto alloc = [&](size_t bytes) { char* p = w; w += ((bytes + 255) / 256) * 256; return p; };
    int*   mode     = (int*)  alloc(256);
    char*  zero_beg = w;
    int*   count    = (int*)  alloc((size_t)BA * 4);
    int*   claim_m  = (int*)  alloc((size_t)BA * 4);
    float* pos_al   = (float*)alloc((size_t)BM * 4);
    float* pos_ov   = (float*)alloc((size_t)BM * 4);
    int*   win_fl   = (int*)  alloc((size_t)BM * NTOPK * 4);
    int*   ovf      = (int*)  alloc((size_t)BM * 4);
    int*   row_cnt  = (int*)  alloc((size_t)BM * 4);
    char*  zero_end = w;
    float* claim_al = (float*)alloc((size_t)BA * 4);
    int*   win_idx  = (int*)  alloc((size_t)BM * NTOPK * 4);
    float* win_al   = (float*)alloc((size_t)BM * NTOPK * 4);
    size_t used = (size_t)(w - (char*)d_ws);
    size_t avail = (ws_size > used + 256) ? (ws_size - used - 256) : 0;
    long long caprow_ll = (long long)(avail / ((size_t)BM * 8));
    int CAPROW = caprow_ll > 1536 ? 1536 : (int)caprow_ll;
    unsigned long long* pool = (unsigned long long*)alloc((size_t)BM * (CAPROW > 0 ? CAPROW : 0) * 8);

    float* out_bb = (float*)d_out;
    float* out_ts = out_bb + (size_t)BA * 4;
    float* out_fg = out_ts + (size_t)BA * C;

    hipMemsetAsync(zero_beg, 0, (size_t)(zero_end - zero_beg), stream);

    k_detect<<<1, 256, 0, stream>>>(mask_gt, BM, mode);

    bool fast = (M <= 64) && (CAPROW >= 64);
    if (fast) {
        int CH = (A + 511) / 512;
        k_cand<<<B * CH, 256, 0, stream>>>(pd_scores, pd_bboxes, anc, gt_labels, gt_bboxes,
                                           mask_gt, mode, row_cnt, pool, ovf, A, C, M, B, CAPROW);
        k_sel<<<BM, 64, 0, stream>>>(pool, row_cnt, ovf, mask_gt, mode, gt_bboxes, anc,
                                     count, win_idx, win_al, win_fl, A, M, CAPROW);
    } else {
        hipMemsetAsync(ovf, 1, (size_t)BM * 4, stream);   // route everything to exact fallback
    }
    k_topk_fb<<<BM, 256, 0, stream>>>(pd_scores, pd_bboxes, anc, gt_labels, gt_bboxes,
                                      mask_gt, mode, ovf, count, win_idx, win_al, win_fl, A, C, M);
    int nclaims = BM * NTOPK;
    k_resolve<<<(nclaims + 255) / 256, 256, 0, stream>>>(
        pd_scores, pd_bboxes, anc, gt_labels, gt_bboxes, mask_gt, mode,
        count, win_idx, win_al, win_fl, claim_m, claim_al, pos_al, pos_ov, A, C, M, nclaims);
    int C4 = C / 4;
    int gBA = (BA + 255) / 256;
    k_final<<<gBA, 256, 0, stream>>>(count, claim_m, claim_al, pos_al, pos_ov,
                                     gt_labels, gt_bboxes, out_bb, out_ts, out_fg, A, M, C4, BA);
}

// Round 11
// 126.438 us; speedup vs baseline: 1.3747x; 1.3747x over previous
//
#include <hip/hip_runtime.h>
#include <cstdint>
#include <cstddef>

#define EPSC 1e-7f
#define EPS9 1e-9f
#define K4PI2 0.40528473456935108577f
#define NTOPK 10
#define GX 16
#define GY 16
#define NCELL (GX * GY)

__device__ __forceinline__ bool mask_at(const unsigned char* mb, int i, int wide) {
    if (wide) return reinterpret_cast<const unsigned int*>(mb)[i] != 0u;
    return mb[i] != 0;
}

__device__ __forceinline__ unsigned long long shfl_xor_u64(unsigned long long v, int off) {
    int lo = __shfl_xor((int)(unsigned)(v & 0xFFFFFFFFull), off);
    int hi = __shfl_xor((int)(unsigned)(v >> 32), off);
    return ((unsigned long long)(unsigned)hi << 32) | (unsigned)lo;
}

__device__ __forceinline__ float ciou_clip(float x1a, float y1a, float x2a, float y2a,
                                           float w1h1, float atan1,
                                           float4 pb, float at2) {
    float w2 = pb.z - pb.x, h2 = pb.w - pb.y + EPSC;
    float iw = fmaxf(fminf(x2a, pb.z) - fmaxf(x1a, pb.x), 0.f);
    float ih = fmaxf(fminf(y2a, pb.w) - fmaxf(y1a, pb.y), 0.f);
    float inter = iw * ih;
    float uni = w1h1 + w2 * h2 - inter;
    float iou = inter / (uni + EPSC);
    float cw = fmaxf(x2a, pb.z) - fminf(x1a, pb.x);
    float ch = fmaxf(y2a, pb.w) - fminf(y1a, pb.y);
    float c2 = cw * cw + ch * ch + EPSC;
    float dx = pb.x + pb.z - x1a - x2a;
    float dy = pb.y + pb.w - y1a - y2a;
    float rho2 = (dx * dx + dy * dy) * 0.25f;
    float dat = at2 - atan1;
    float vv = K4PI2 * dat * dat;
    float aa = vv / (vv - iou + (1.f + EPSC));
    return fmaxf(iou - (rho2 / c2 + vv * aa), 0.f);
}

// K0: detect mask_gt memory layout. wide iff all n/4 leading words are {0,1,1.0f}
__global__ void k_detect(const unsigned char* __restrict__ mask, int n, int* __restrict__ mode) {
    __shared__ int bad;
    if (threadIdx.x == 0) bad = 0;
    __syncthreads();
    const unsigned int* w = reinterpret_cast<const unsigned int*>(mask);
    int nw = n >> 2;
    for (int i = threadIdx.x; i < nw; i += 256) {
        unsigned int v = w[i];
        if (v != 0u && v != 1u && v != 0x3f800000u) atomicOr(&bad, 1);
    }
    __syncthreads();
    if (threadIdx.x == 0) mode[0] = bad ? 0 : 1;
}

// K1: bin anchors into a GX x GY grid (single block). Bin order is nondeterministic
// (atomics) but all consumers are order-independent -> deterministic outputs.
__global__ __launch_bounds__(1024) void k_bin(
    const float* __restrict__ anc, int A,
    int* __restrict__ cell_start, int* __restrict__ binned, float* __restrict__ gp)
{
    __shared__ int h[NCELL];
    __shared__ int cs[NCELL + 1];
    __shared__ int cur[NCELL];
    __shared__ float rmnx[16], rmny[16], rmxx[16], rmxy[16];
    __shared__ float s_gp[4];

    int tid = threadIdx.x;
    int lane = tid & 63, wid = tid >> 6;
    const float2* an2 = reinterpret_cast<const float2*>(anc);

    // pass 0: min/max of anchor coords
    float mnx = 3e38f, mny = 3e38f, mxx = -3e38f, mxy = -3e38f;
    for (int i = tid; i < A; i += 1024) {
        float2 p = an2[i];
        mnx = fminf(mnx, p.x); mny = fminf(mny, p.y);
        mxx = fmaxf(mxx, p.x); mxy = fmaxf(mxy, p.y);
    }
#pragma unroll
    for (int off = 32; off; off >>= 1) {
        mnx = fminf(mnx, __shfl_xor(mnx, off));
        mny = fminf(mny, __shfl_xor(mny, off));
        mxx = fmaxf(mxx, __shfl_xor(mxx, off));
        mxy = fmaxf(mxy, __shfl_xor(mxy, off));
    }
    if (lane == 0) { rmnx[wid] = mnx; rmny[wid] = mny; rmxx[wid] = mxx; rmxy[wid] = mxy; }
    if (tid < NCELL) h[tid] = 0;
    __syncthreads();
    if (tid == 0) {
        float a = 3e38f, b2 = 3e38f, c = -3e38f, d = -3e38f;
        for (int i = 0; i < 16; ++i) {
            a = fminf(a, rmnx[i]); b2 = fminf(b2, rmny[i]);
            c = fmaxf(c, rmxx[i]); d = fmaxf(d, rmxy[i]);
        }
        float rx = fmaxf(c - a, 1e-6f), ry = fmaxf(d - b2, 1e-6f);
        s_gp[0] = a; s_gp[1] = b2;
        s_gp[2] = (float)GX / rx; s_gp[3] = (float)GY / ry;
        gp[0] = s_gp[0]; gp[1] = s_gp[1]; gp[2] = s_gp[2]; gp[3] = s_gp[3];
    }
    __syncthreads();
    float ox = s_gp[0], oy = s_gp[1], ivx = s_gp[2], ivy = s_gp[3];

    // pass 1: histogram
    for (int i = tid; i < A; i += 1024) {
        float2 p = an2[i];
        int cx = min(GX - 1, max(0, (int)floorf((p.x - ox) * ivx)));
        int cy = min(GY - 1, max(0, (int)floorf((p.y - oy) * ivy)));
        atomicAdd(&h[cy * GX + cx], 1);
    }
    __syncthreads();
    // exclusive prefix (wave 0, shfl_up scan per 64-chunk)
    if (wid == 0) {
        int base = 0;
        for (int ch = 0; ch < NCELL / 64; ++ch) {
            int v = h[ch * 64 + lane];
            int inc = v;
            for (int off = 1; off < 64; off <<= 1) {
                int u = __shfl_up(inc, off);
                if (lane >= off) inc += u;
            }
            cs[ch * 64 + lane] = base + inc - v;
            base += __shfl(inc, 63);
        }
        if (lane == 0) cs[NCELL] = base;
    }
    __syncthreads();
    if (tid <= NCELL) cell_start[tid] = cs[tid];
    if (tid < NCELL) cur[tid] = cs[tid];
    __syncthreads();
    // pass 2: scatter
    for (int i = tid; i < A; i += 1024) {
        float2 p = an2[i];
        int cx = min(GX - 1, max(0, (int)floorf((p.x - ox) * ivx)));
        int cy = min(GY - 1, max(0, (int)floorf((p.y - oy) * ivy)));
        int slot = atomicAdd(&cur[cy * GX + cx], 1);
        binned[slot] = i;
    }
}

// K2: one wave per (b,m). Visit only grid cells overlapping the gt box; inline metric;
// per-lane sorted register top-10 (lossless); 10-round butterfly tournament
// == lax.top_k (value desc, idx asc) via u64 key (val_bits<<32)|~idx. No LDS/barriers.
__global__ __launch_bounds__(64) void k_sel(
    const float* __restrict__ pd_scores, const float* __restrict__ pd_bboxes,
    const float* __restrict__ anc, const float* __restrict__ gt_labels,
    const float* __restrict__ gt_bboxes, const unsigned char* __restrict__ mask_gt,
    const int* __restrict__ mode, const int* __restrict__ cell_start,
    const int* __restrict__ binned, const float* __restrict__ gp,
    int* __restrict__ count, int* __restrict__ win_idx, float* __restrict__ win_al,
    int* __restrict__ win_fl,
    int A, int C, int M, int B)
{
    int bid = blockIdx.x;
    int b = bid % B, m = bid / B;        // XCD swizzle: same-b rows land on one XCD (B%8==0)
    int row = b * M + m;
    if (!mask_at(mask_gt, row, mode[0])) return;   // win_fl pre-zeroed -> no claims
    int lane = threadIdx.x;

    float4 g = reinterpret_cast<const float4*>(gt_bboxes)[row];
    float x1a = g.x, y1a = g.y, x2a = g.z, y2a = g.w;
    float w1 = x2a - x1a, h1 = y2a - y1a + EPSC;
    float w1h1 = w1 * h1;
    float atan1 = atanf(w1 / h1);
    int lbl = (int)gt_labels[row];

    float ox = gp[0], oy = gp[1], ivx = gp[2], ivy = gp[3];
    // identical expressions to k_bin; monotone -> cannot miss any in-box anchor
    int cx0 = min(GX - 1, max(0, (int)floorf((x1a - ox) * ivx)));
    int cx1 = min(GX - 1, max(0, (int)floorf((x2a - ox) * ivx)));
    int cy0 = min(GY - 1, max(0, (int)floorf((y1a - oy) * ivy)));
    int cy1 = min(GY - 1, max(0, (int)floorf((y2a - oy) * ivy)));

    const float2* an2 = reinterpret_cast<const float2*>(anc);
    const float4* pb4 = reinterpret_cast<const float4*>(pd_bboxes + (size_t)b * A * 4);
    const float*  ps  = pd_scores + (size_t)b * A * C;

    unsigned long long tv[NTOPK];
#pragma unroll
    for (int j = 0; j < NTOPK; ++j) tv[j] = 0;
    int pcnt = 0;

    for (int cy = cy0; cy <= cy1; ++cy) {
        for (int cx = cx0; cx <= cx1; ++cx) {
            int c = cy * GX + cx;
            int s = cell_start[c], e = cell_start[c + 1];
            for (int i = s + lane; i < e; i += 64) {
                int a = binned[i];
                float2 ap = an2[a];
                bool in = (ap.x - x1a > EPS9) & (ap.y - y1a > EPS9) &
                          (x2a - ap.x > EPS9) & (y2a - ap.y > EPS9);
                if (in) {
                    float4 pb = pb4[a];
                    float w2 = pb.z - pb.x, h2 = pb.w - pb.y + EPSC;
                    float at2 = atanf(w2 / h2);
                    float ovl = ciou_clip(x1a, y1a, x2a, y2a, w1h1, atan1, pb, at2);
                    float sc = (lbl >= 0) ? ps[(size_t)a * C + lbl] : 0.f;
                    float o2 = ovl * ovl;
                    float val = sqrtf(sc) * (o2 * o2 * o2);
                    pcnt += (val > 0.f) ? 1 : 0;
                    unsigned long long kk =
                        ((unsigned long long)__float_as_uint(val) << 32) | (unsigned)(~(unsigned)a);
                    if (kk > tv[NTOPK - 1]) {
                        tv[NTOPK - 1] = kk;
#pragma unroll
                        for (int j = NTOPK - 1; j > 0; --j)
                            if (tv[j] > tv[j - 1]) {
                                unsigned long long t = tv[j]; tv[j] = tv[j - 1]; tv[j - 1] = t;
                            }
                    }
                }
            }
        }
    }

#pragma unroll
    for (int off = 32; off; off >>= 1) pcnt += __shfl_xor(pcnt, off);
    int p = pcnt;
    int rp = p < NTOPK ? p : NTOPK;
    size_t bA = (size_t)b * A;
    int base_o = row * NTOPK;

    // 3a: positive rounds — register head + wave-max butterfly, winner pops
    for (int k = 0; k < rp; ++k) {
        unsigned long long head = tv[0];
        unsigned long long best = head;
#pragma unroll
        for (int off = 32; off; off >>= 1) {
            unsigned long long o = shfl_xor_u64(best, off);
            if (o > best) best = o;
        }
        if (head == best && head != 0ull) {      // unique owner (keys unique by idx)
            int a = (int)(~(unsigned)(best & 0xFFFFFFFFull));
            int o = base_o + k;
            win_idx[o] = a;
            win_al[o]  = __uint_as_float((unsigned)(best >> 32));
            win_fl[o]  = 1;
            atomicAdd(&count[bA + a], 1);
#pragma unroll
            for (int j = 0; j < NTOPK - 1; ++j) tv[j] = tv[j + 1];
            tv[NTOPK - 1] = 0;
        }
    }

    // 3b (rare: p < 10): fill with smallest-index zero-val anchors; in-box zero-vals
    // (retained in tv: per-lane rank of the k-th smallest zero <= p + k <= 10) claim.
    if (rp < NTOPK) {
        int iters = (A + 63 - lane) / 64;
        int zp = 0;
        for (int k = rp; k < NTOPK; ++k) {
            unsigned zprop = 0xFFFFFFFFu;        // next out-of-box anchor (padding, no claim)
            while (zp < iters) {
                int a = lane + zp * 64;
                float2 ap = an2[a];
                bool in = (ap.x - x1a > EPS9) & (ap.y - y1a > EPS9) &
                          (x2a - ap.x > EPS9) & (y2a - ap.y > EPS9);
                if (!in) { zprop = (unsigned)a; break; }
                ++zp;
            }
            unsigned cprop = 0xFFFFFFFFu;        // unconsumed in-box zero-val (regs)
#pragma unroll
            for (int j = 0; j < NTOPK; ++j) {
                unsigned long long kk = tv[j];
                if (kk != 0ull && kk < (1ull << 32)) {
                    unsigned idx2 = ~(unsigned)kk;
                    if (idx2 < cprop) cprop = idx2;
                }
            }
            unsigned prop = zprop < cprop ? zprop : cprop;
            unsigned bm_ = prop;
#pragma unroll
            for (int off = 32; off; off >>= 1) {
                unsigned o = (unsigned)__shfl_xor((int)bm_, off);
                if (o < bm_) bm_ = o;
            }
            if (bm_ != 0xFFFFFFFFu) {
                if (cprop == bm_ && cprop < zprop) {
                    int o = base_o + k;
                    win_idx[o] = (int)bm_; win_al[o] = 0.f; win_fl[o] = 1;
                    atomicAdd(&count[bA + bm_], 1);
                    unsigned long long wkk = (unsigned long long)(unsigned)(~bm_);
#pragma unroll
                    for (int j = 0; j < NTOPK; ++j) if (tv[j] == wkk) tv[j] = 0;
                } else if (zprop == bm_ && zprop < cprop) {
                    ++zp;
                }
            }
        }
    }
}

// K3: claim resolution + fused pos_al/pos_ov atomicMax (winner CIoU recomputed)
__global__ void k_resolve(
    const float* __restrict__ pd_scores, const float* __restrict__ pd_bboxes,
    const float* __restrict__ anc, const float* __restrict__ gt_labels,
    const float* __restrict__ gt_bboxes, const unsigned char* __restrict__ mask_gt,
    const int* __restrict__ mode,
    const int* __restrict__ count, const int* __restrict__ win_idx,
    const float* __restrict__ win_al, const int* __restrict__ win_fl,
    int* __restrict__ claim_m, float* __restrict__ claim_al,
    float* __restrict__ pos_al, float* __restrict__ pos_ov,
    int A, int C, int M, int total)
{
    int t = blockIdx.x * 256 + threadIdx.x;
    if (t >= total) return;
    int bm = t / NTOPK;
    int b = bm / M, m = bm % M;
    if (!win_fl[t]) return;
    int a = win_idx[t];
    size_t ba = (size_t)b * A + a;
    int cnt = count[ba];
    float al, ov; int mm_out;
    if (cnt == 1) {
        mm_out = m; al = win_al[t];
        float4 gg = reinterpret_cast<const float4*>(gt_bboxes)[b * M + m];
        float w1 = gg.z - gg.x, h1 = gg.w - gg.y + EPSC;
        float4 pb = reinterpret_cast<const float4*>(pd_bboxes)[ba];
        float w2 = pb.z - pb.x, h2p = pb.w - pb.y + EPSC;
        ov = ciou_clip(gg.x, gg.y, gg.z, gg.w, w1 * h1, atanf(w1 / h1), pb, atanf(w2 / h2p));
    } else {
        int wide = mode[0];
        float4 pb = reinterpret_cast<const float4*>(pd_bboxes)[ba];
        float2 ap = reinterpret_cast<const float2*>(anc)[a];
        float w2 = pb.z - pb.x, h2p = pb.w - pb.y + EPSC;
        float at2 = atanf(w2 / h2p);
        float best_ov = -1.f; int best_m = 0, best_valid = 0;
        for (int mm = 0; mm < M; ++mm) {
            float4 gg = reinterpret_cast<const float4*>(gt_bboxes)[b * M + mm];
            bool in = (ap.x - gg.x > EPS9) && (ap.y - gg.y > EPS9) &&
                      (gg.z - ap.x > EPS9) && (gg.w - ap.y > EPS9);
            bool valid = in && mask_at(mask_gt, b * M + mm, wide);
            float ovv = 0.f;
            if (valid) {
                float w1 = gg.z - gg.x, h1 = gg.w - gg.y + EPSC;
                ovv = ciou_clip(gg.x, gg.y, gg.z, gg.w, w1 * h1, atanf(w1 / h1), pb, at2);
            }
            if (ovv > best_ov) { best_ov = ovv; best_m = mm; best_valid = valid ? 1 : 0; }
        }
        int lb = (int)gt_labels[b * M + best_m];
        float sc = (best_valid && lb >= 0) ? pd_scores[ba * C + lb] : 0.f;
        float o2 = best_ov * best_ov;
        mm_out = best_m; al = sqrtf(sc) * (o2 * o2 * o2); ov = best_ov;
    }
    claim_m[ba]  = mm_out;
    claim_al[ba] = al;
    atomicMax((unsigned int*)&pos_al[b * M + mm_out], __float_as_uint(al));
    atomicMax((unsigned int*)&pos_ov[b * M + mm_out], __float_as_uint(ov));
}

// K4: fused finalize — per-anchor (bb, fg, nv, lb) then coalesced score writes
__global__ __launch_bounds__(256) void k_final(
    const int* __restrict__ count, const int* __restrict__ claim_m,
    const float* __restrict__ claim_al,
    const float* __restrict__ pos_al, const float* __restrict__ pos_ov,
    const float* __restrict__ gt_labels, const float* __restrict__ gt_bboxes,
    float* __restrict__ out_bb, float* __restrict__ out_ts, float* __restrict__ out_fg,
    int A, int M, int C4, int BA)
{
    __shared__ float s_nv[256];
    __shared__ int   s_lb[256];
    int base_ba = blockIdx.x * 256;
    int tid = threadIdx.x;
    int ba = base_ba + tid;
    if (ba < BA) {
        int b = ba / A;
        int cnt = count[ba];
        int m = claim_m[ba];                   // 0 for background (memset)
        float4 g = reinterpret_cast<const float4*>(gt_bboxes)[b * M + m];
        reinterpret_cast<float4*>(out_bb)[ba] = g;
        float nv = 0.f; int lb = -1;
        if (cnt > 0) {
            lb = max((int)gt_labels[b * M + m], 0);
            nv = claim_al[ba] * pos_ov[b * M + m] / (pos_al[b * M + m] + EPS9);
        }
        out_fg[ba] = (cnt > 0) ? 1.f : 0.f;
        s_nv[tid] = nv; s_lb[tid] = lb;
    } else { s_nv[tid] = 0.f; s_lb[tid] = -1; }
    __syncthreads();
    float4* ts4 = reinterpret_cast<float4*>(out_ts);
    size_t fbase = (size_t)base_ba * C4;
    for (int j = 0; j < C4; ++j) {
        int fl = j * 256 + tid;                // consecutive tid -> consecutive float4s
        int la = fl / C4;
        int ch = fl - la * C4;
        int ba2 = base_ba + la;
        if (ba2 < BA) {
            float nv = s_nv[la];
            int lb = s_lb[la];
            int c0 = ch * 4;
            float4 o;
            o.x = (c0     == lb) ? nv : 0.f;
            o.y = (c0 + 1 == lb) ? nv : 0.f;
            o.z = (c0 + 2 == lb) ? nv : 0.f;
            o.w = (c0 + 3 == lb) ? nv : 0.f;
            ts4[fbase + fl] = o;
        }
    }
}

extern "C" void kernel_launch(void* const* d_in, const int* in_sizes, int n_in,
                              void* d_out, int out_size, void* d_ws, size_t ws_size,
                              hipStream_t stream) {
    const float* pd_scores = (const float*)d_in[0];
    const float* pd_bboxes = (const float*)d_in[1];
    const float* anc       = (const float*)d_in[2];
    const float* gt_labels = (const float*)d_in[3];
    const float* gt_bboxes = (const float*)d_in[4];
    const unsigned char* mask_gt = (const unsigned char*)d_in[5];

    int A  = in_sizes[2] / 2;
    int BA = in_sizes[1] / 4;
    int B  = BA / A;
    int C  = in_sizes[0] / BA;
    int M  = in_sizes[3] / B;
    int BM = B * M;

    // workspace carve (256B-aligned bumps; zeroed span is contiguous)
    char* w = (char*)d_ws;
    auto alloc = [&](size_t bytes) { char* p = w; w += ((bytes + 255) / 256) * 256; return p; };
    int*   mode       = (int*)  alloc(256);
    char*  zero_beg   = w;
    int*   count      = (int*)  alloc((size_t)BA * 4);
    int*   claim_m    = (int*)  alloc((size_t)BA * 4);
    float* pos_al     = (float*)alloc((size_t)BM * 4);
    float* pos_ov     = (float*)alloc((size_t)BM * 4);
    int*   win_fl     = (int*)  alloc((size_t)BM * NTOPK * 4);
    char*  zero_end   = w;
    float* claim_al   = (float*)alloc((size_t)BA * 4);
    int*   win_idx    = (int*)  alloc((size_t)BM * NTOPK * 4);
    float* win_al     = (float*)alloc((size_t)BM * NTOPK * 4);
    int*   cell_start = (int*)  alloc((size_t)(NCELL + 1) * 4);
    int*   binned     = (int*)  alloc((size_t)A * 4);
    float* gp         = (float*)alloc(256);

    float* out_bb = (float*)d_out;
    float* out_ts = out_bb + (size_t)BA * 4;
    float* out_fg = out_ts + (size_t)BA * C;

    hipMemsetAsync(zero_beg, 0, (size_t)(zero_end - zero_beg), stream);

    k_detect<<<1, 256, 0, stream>>>(mask_gt, BM, mode);
    k_bin<<<1, 1024, 0, stream>>>(anc, A, cell_start, binned, gp);
    k_sel<<<BM, 64, 0, stream>>>(pd_scores, pd_bboxes, anc, gt_labels, gt_bboxes, mask_gt,
                                 mode, cell_start, binned, gp,
                                 count, win_idx, win_al, win_fl, A, C, M, B);
    int nclaims = BM * NTOPK;
    k_resolve<<<(nclaims + 255) / 256, 256, 0, stream>>>(
        pd_scores, pd_bboxes, anc, gt_labels, gt_bboxes, mask_gt, mode,
        count, win_idx, win_al, win_fl, claim_m, claim_al, pos_al, pos_ov, A, C, M, nclaims);
    int C4 = C / 4;
    int gBA = (BA + 255) / 256;
    k_final<<<gBA, 256, 0, stream>>>(count, claim_m, claim_al, pos_al, pos_ov,
                                     gt_labels, gt_bboxes, out_bb, out_ts, out_fg, A, M, C4, BA);
}

// Round 12
// 102.412 us; speedup vs baseline: 1.6973x; 1.2346x over previous
//
#include <hip/hip_runtime.h>
#include <cstdint>
#include <cstddef>

#define EPSC 1e-7f
#define EPS9 1e-9f
#define K4PI2 0.40528473456935108577f
#define NTOPK 10
#define GX 16
#define GY 16
#define NCELL (GX * GY)

__device__ __forceinline__ bool mask_at(const unsigned char* mb, int i, int wide) {
    if (wide) return reinterpret_cast<const unsigned int*>(mb)[i] != 0u;
    return mb[i] != 0;
}

__device__ __forceinline__ unsigned long long shfl_xor_u64(unsigned long long v, int off) {
    int lo = __shfl_xor((int)(unsigned)(v & 0xFFFFFFFFull), off);
    int hi = __shfl_xor((int)(unsigned)(v >> 32), off);
    return ((unsigned long long)(unsigned)hi << 32) | (unsigned)lo;
}

__device__ __forceinline__ float ciou_clip(float x1a, float y1a, float x2a, float y2a,
                                           float w1h1, float atan1,
                                           float4 pb, float at2) {
    float w2 = pb.z - pb.x, h2 = pb.w - pb.y + EPSC;
    float iw = fmaxf(fminf(x2a, pb.z) - fmaxf(x1a, pb.x), 0.f);
    float ih = fmaxf(fminf(y2a, pb.w) - fmaxf(y1a, pb.y), 0.f);
    float inter = iw * ih;
    float uni = w1h1 + w2 * h2 - inter;
    float iou = inter / (uni + EPSC);
    float cw = fmaxf(x2a, pb.z) - fminf(x1a, pb.x);
    float ch = fmaxf(y2a, pb.w) - fminf(y1a, pb.y);
    float c2 = cw * cw + ch * ch + EPSC;
    float dx = pb.x + pb.z - x1a - x2a;
    float dy = pb.y + pb.w - y1a - y2a;
    float rho2 = (dx * dx + dy * dy) * 0.25f;
    float dat = at2 - atan1;
    float vv = K4PI2 * dat * dat;
    float aa = vv / (vv - iou + (1.f + EPSC));
    return fmaxf(iou - (rho2 / c2 + vv * aa), 0.f);
}

// K0: fused mask-layout detect + spatial binning (single 1024-thread block).
// Bin order is nondeterministic (atomics) but consumers are order-independent.
__global__ __launch_bounds__(1024) void k_prep(
    const unsigned char* __restrict__ mask, int nmask, int* __restrict__ mode,
    const float* __restrict__ anc, int A,
    int* __restrict__ cell_start, int* __restrict__ binned, float* __restrict__ gp)
{
    __shared__ int h[NCELL];
    __shared__ int cs[NCELL + 1];
    __shared__ int cur[NCELL];
    __shared__ float rmnx[16], rmny[16], rmxx[16], rmxy[16];
    __shared__ float s_gp[4];
    __shared__ int bad;

    int tid = threadIdx.x;
    int lane = tid & 63, wid = tid >> 6;
    const float2* an2 = reinterpret_cast<const float2*>(anc);

    if (tid == 0) bad = 0;
    if (tid < NCELL) h[tid] = 0;
    __syncthreads();

    // mask layout detect: wide iff all nmask/4 leading words in {0,1,1.0f}
    const unsigned int* mw = reinterpret_cast<const unsigned int*>(mask);
    int nw = nmask >> 2;
    for (int i = tid; i < nw; i += 1024) {
        unsigned int v = mw[i];
        if (v != 0u && v != 1u && v != 0x3f800000u) atomicOr(&bad, 1);
    }

    // pass 0: min/max of anchor coords
    float mnx = 3e38f, mny = 3e38f, mxx = -3e38f, mxy = -3e38f;
    for (int i = tid; i < A; i += 1024) {
        float2 p = an2[i];
        mnx = fminf(mnx, p.x); mny = fminf(mny, p.y);
        mxx = fmaxf(mxx, p.x); mxy = fmaxf(mxy, p.y);
    }
#pragma unroll
    for (int off = 32; off; off >>= 1) {
        mnx = fminf(mnx, __shfl_xor(mnx, off));
        mny = fminf(mny, __shfl_xor(mny, off));
        mxx = fmaxf(mxx, __shfl_xor(mxx, off));
        mxy = fmaxf(mxy, __shfl_xor(mxy, off));
    }
    if (lane == 0) { rmnx[wid] = mnx; rmny[wid] = mny; rmxx[wid] = mxx; rmxy[wid] = mxy; }
    __syncthreads();
    if (tid == 0) {
        mode[0] = bad ? 0 : 1;
        float a = 3e38f, b2 = 3e38f, c = -3e38f, d = -3e38f;
        for (int i = 0; i < 16; ++i) {
            a = fminf(a, rmnx[i]); b2 = fminf(b2, rmny[i]);
            c = fmaxf(c, rmxx[i]); d = fmaxf(d, rmxy[i]);
        }
        float rx = fmaxf(c - a, 1e-6f), ry = fmaxf(d - b2, 1e-6f);
        s_gp[0] = a; s_gp[1] = b2;
        s_gp[2] = (float)GX / rx; s_gp[3] = (float)GY / ry;
        gp[0] = s_gp[0]; gp[1] = s_gp[1]; gp[2] = s_gp[2]; gp[3] = s_gp[3];
    }
    __syncthreads();
    float ox = s_gp[0], oy = s_gp[1], ivx = s_gp[2], ivy = s_gp[3];

    // pass 1: histogram
    for (int i = tid; i < A; i += 1024) {
        float2 p = an2[i];
        int cx = min(GX - 1, max(0, (int)floorf((p.x - ox) * ivx)));
        int cy = min(GY - 1, max(0, (int)floorf((p.y - oy) * ivy)));
        atomicAdd(&h[cy * GX + cx], 1);
    }
    __syncthreads();
    // exclusive prefix (wave 0, shfl_up scan per 64-chunk)
    if (wid == 0) {
        int base = 0;
        for (int ch = 0; ch < NCELL / 64; ++ch) {
            int v = h[ch * 64 + lane];
            int inc = v;
            for (int off = 1; off < 64; off <<= 1) {
                int u = __shfl_up(inc, off);
                if (lane >= off) inc += u;
            }
            cs[ch * 64 + lane] = base + inc - v;
            base += __shfl(inc, 63);
        }
        if (lane == 0) cs[NCELL] = base;
    }
    __syncthreads();
    if (tid <= NCELL) cell_start[tid] = cs[tid];
    if (tid < NCELL) cur[tid] = cs[tid];
    __syncthreads();
    // pass 2: scatter
    for (int i = tid; i < A; i += 1024) {
        float2 p = an2[i];
        int cx = min(GX - 1, max(0, (int)floorf((p.x - ox) * ivx)));
        int cy = min(GY - 1, max(0, (int)floorf((p.y - oy) * ivy)));
        int slot = atomicAdd(&cur[cy * GX + cx], 1);
        binned[slot] = i;
    }
}

// K2: one 256-thread block (4 waves) per (b,m). Waves split the gt's overlapped cells;
// per-lane sorted register top-10 -> wave top-10 (butterfly) -> LDS -> wave-0 merge of
// 40 keys (one per lane). Order == lax.top_k (value desc, idx asc), key (val<<32)|~idx.
__global__ __launch_bounds__(256) void k_sel(
    const float* __restrict__ pd_scores, const float* __restrict__ pd_bboxes,
    const float* __restrict__ anc, const float* __restrict__ gt_labels,
    const float* __restrict__ gt_bboxes, const unsigned char* __restrict__ mask_gt,
    const int* __restrict__ mode, const int* __restrict__ cell_start,
    const int* __restrict__ binned, const float* __restrict__ gp,
    int* __restrict__ count, int* __restrict__ win_idx, float* __restrict__ win_al,
    int* __restrict__ win_fl,
    int A, int C, int M, int B)
{
    __shared__ unsigned long long keys40[4 * NTOPK];
    __shared__ int s_pc[4];

    int bid = blockIdx.x;
    int b = bid % B, m = bid / B;        // XCD swizzle: same-b rows on one XCD (B%8==0)
    int row = b * M + m;
    if (!mask_at(mask_gt, row, mode[0])) return;   // win_fl pre-zeroed -> no claims
    int tid = threadIdx.x;
    int lane = tid & 63, wid = tid >> 6;

    float4 g = reinterpret_cast<const float4*>(gt_bboxes)[row];
    float x1a = g.x, y1a = g.y, x2a = g.z, y2a = g.w;
    float w1 = x2a - x1a, h1 = y2a - y1a + EPSC;
    float w1h1 = w1 * h1;
    float atan1 = atanf(w1 / h1);
    int lbl = (int)gt_labels[row];

    float ox = gp[0], oy = gp[1], ivx = gp[2], ivy = gp[3];
    // identical expressions to k_prep; monotone -> cannot miss any in-box anchor
    int cx0 = min(GX - 1, max(0, (int)floorf((x1a - ox) * ivx)));
    int cx1 = min(GX - 1, max(0, (int)floorf((x2a - ox) * ivx)));
    int cy0 = min(GY - 1, max(0, (int)floorf((y1a - oy) * ivy)));
    int cy1 = min(GY - 1, max(0, (int)floorf((y2a - oy) * ivy)));
    int nx = cx1 - cx0 + 1;
    int nbox = nx * (cy1 - cy0 + 1);

    const float2* an2 = reinterpret_cast<const float2*>(anc);
    const float4* pb4 = reinterpret_cast<const float4*>(pd_bboxes + (size_t)b * A * 4);
    const float*  ps  = pd_scores + (size_t)b * A * C;

    unsigned long long tv[NTOPK];
#pragma unroll
    for (int j = 0; j < NTOPK; ++j) tv[j] = 0;
    int pcnt = 0;

    // waves split cells: ci % 4 == wid  (each anchor in exactly one cell -> keys unique)
    for (int ci = wid; ci < nbox; ci += 4) {
        int cy = cy0 + ci / nx, cx = cx0 + ci % nx;
        int c = cy * GX + cx;
        int s = cell_start[c], e = cell_start[c + 1];
        for (int i = s + lane; i < e; i += 64) {
            int a = binned[i];
            float2 ap = an2[a];
            bool in = (ap.x - x1a > EPS9) & (ap.y - y1a > EPS9) &
                      (x2a - ap.x > EPS9) & (y2a - ap.y > EPS9);
            if (in) {
                float4 pb = pb4[a];
                float w2 = pb.z - pb.x, h2 = pb.w - pb.y + EPSC;
                float at2 = atanf(w2 / h2);
                float ovl = ciou_clip(x1a, y1a, x2a, y2a, w1h1, atan1, pb, at2);
                float sc = (lbl >= 0) ? ps[(size_t)a * C + lbl] : 0.f;
                float o2 = ovl * ovl;
                float val = sqrtf(sc) * (o2 * o2 * o2);
                pcnt += (val > 0.f) ? 1 : 0;
                unsigned long long kk =
                    ((unsigned long long)__float_as_uint(val) << 32) | (unsigned)(~(unsigned)a);
                if (kk > tv[NTOPK - 1]) {
                    tv[NTOPK - 1] = kk;
#pragma unroll
                    for (int j = NTOPK - 1; j > 0; --j)
                        if (tv[j] > tv[j - 1]) {
                            unsigned long long t = tv[j]; tv[j] = tv[j - 1]; tv[j - 1] = t;
                        }
                }
            }
        }
    }

    // per-wave positive count + wave top-10 extraction into LDS
#pragma unroll
    for (int off = 32; off; off >>= 1) pcnt += __shfl_xor(pcnt, off);
    if (lane == 0) s_pc[wid] = pcnt;
#pragma unroll
    for (int k = 0; k < NTOPK; ++k) {
        unsigned long long head = tv[0];
        unsigned long long best = head;
#pragma unroll
        for (int off = 32; off; off >>= 1) {
            unsigned long long o = shfl_xor_u64(best, off);
            if (o > best) best = o;
        }
        if (lane == 0) keys40[wid * NTOPK + k] = best;
        if (head == best && head != 0ull) {   // unique owner pops
#pragma unroll
            for (int j = 0; j < NTOPK - 1; ++j) tv[j] = tv[j + 1];
            tv[NTOPK - 1] = 0;
        }
    }
    __syncthreads();

    if (wid != 0) return;                      // merge is single-wave
    int p = s_pc[0] + s_pc[1] + s_pc[2] + s_pc[3];
    int rp = p < NTOPK ? p : NTOPK;
    unsigned long long key = (lane < 4 * NTOPK) ? keys40[lane] : 0;
    size_t bA = (size_t)b * A;
    int base_o = row * NTOPK;

    // 3a: positive rounds — butterfly max over the 40 merged keys, owner emits & clears
    for (int k = 0; k < rp; ++k) {
        unsigned long long best = key;
#pragma unroll
        for (int off = 32; off; off >>= 1) {
            unsigned long long o = shfl_xor_u64(best, off);
            if (o > best) best = o;
        }
        if (key == best && best != 0ull) {     // unique owner (keys unique)
            int a = (int)(~(unsigned)(best & 0xFFFFFFFFull));
            int o = base_o + k;
            win_idx[o] = a;
            win_al[o]  = __uint_as_float((unsigned)(best >> 32));
            win_fl[o]  = 1;
            atomicAdd(&count[bA + a], 1);
            key = 0;
        }
    }

    // 3b (rare: p < 10): fill with smallest-index zero-val anchors; in-box zero-vals
    // (retained through both top-10 stages: global rank of any needed element <= 10) claim.
    if (rp < NTOPK) {
        int iters = (A + 63 - lane) / 64;
        int zp = 0;
        for (int k = rp; k < NTOPK; ++k) {
            unsigned zprop = 0xFFFFFFFFu;      // next out-of-box anchor (padding, no claim)
            while (zp < iters) {
                int a = lane + zp * 64;
                float2 ap = an2[a];
                bool in = (ap.x - x1a > EPS9) & (ap.y - y1a > EPS9) &
                          (x2a - ap.x > EPS9) & (y2a - ap.y > EPS9);
                if (!in) { zprop = (unsigned)a; break; }
                ++zp;
            }
            // unconsumed in-box zero-val among merged keys (this lane holds one key)
            unsigned cprop = (key != 0ull && key < (1ull << 32)) ? ~(unsigned)key : 0xFFFFFFFFu;
            unsigned prop = zprop < cprop ? zprop : cprop;
            unsigned bm_ = prop;
#pragma unroll
            for (int off = 32; off; off >>= 1) {
                unsigned o = (unsigned)__shfl_xor((int)bm_, off);
                if (o < bm_) bm_ = o;
            }
            if (bm_ != 0xFFFFFFFFu) {
                if (cprop == bm_ && cprop < zprop) {
                    // winner is an in-box zero-val; owner lane emits (cprop unique)
                    int o = base_o + k;
                    win_idx[o] = (int)bm_; win_al[o] = 0.f; win_fl[o] = 1;
                    atomicAdd(&count[bA + bm_], 1);
                    key = 0;
                } else if (zprop == bm_ && zprop < cprop) {
                    ++zp;                      // padding slot consumed, no claim
                }
            }
        }
    }
}

// K3: claim resolution + fused pos_al/pos_ov atomicMax (winner CIoU recomputed)
__global__ void k_resolve(
    const float* __restrict__ pd_scores, const float* __restrict__ pd_bboxes,
    const float* __restrict__ anc, const float* __restrict__ gt_labels,
    const float* __restrict__ gt_bboxes, const unsigned char* __restrict__ mask_gt,
    const int* __restrict__ mode,
    const int* __restrict__ count, const int* __restrict__ win_idx,
    const float* __restrict__ win_al, const int* __restrict__ win_fl,
    int* __restrict__ claim_m, float* __restrict__ claim_al,
    float* __restrict__ pos_al, float* __restrict__ pos_ov,
    int A, int C, int M, int total)
{
    int t = blockIdx.x * 256 + threadIdx.x;
    if (t >= total) return;
    int bm = t / NTOPK;
    int b = bm / M, m = bm % M;
    if (!win_fl[t]) return;
    int a = win_idx[t];
    size_t ba = (size_t)b * A + a;
    int cnt = count[ba];
    float al, ov; int mm_out;
    if (cnt == 1) {
        mm_out = m; al = win_al[t];
        float4 gg = reinterpret_cast<const float4*>(gt_bboxes)[b * M + m];
        float w1 = gg.z - gg.x, h1 = gg.w - gg.y + EPSC;
        float4 pb = reinterpret_cast<const float4*>(pd_bboxes)[ba];
        float w2 = pb.z - pb.x, h2p = pb.w - pb.y + EPSC;
        ov = ciou_clip(gg.x, gg.y, gg.z, gg.w, w1 * h1, atanf(w1 / h1), pb, atanf(w2 / h2p));
    } else {
        int wide = mode[0];
        float4 pb = reinterpret_cast<const float4*>(pd_bboxes)[ba];
        float2 ap = reinterpret_cast<const float2*>(anc)[a];
        float w2 = pb.z - pb.x, h2p = pb.w - pb.y + EPSC;
        float at2 = atanf(w2 / h2p);
        float best_ov = -1.f; int best_m = 0, best_valid = 0;
        for (int mm = 0; mm < M; ++mm) {
            float4 gg = reinterpret_cast<const float4*>(gt_bboxes)[b * M + mm];
            bool in = (ap.x - gg.x > EPS9) && (ap.y - gg.y > EPS9) &&
                      (gg.z - ap.x > EPS9) && (gg.w - ap.y > EPS9);
            bool valid = in && mask_at(mask_gt, b * M + mm, wide);
            float ovv = 0.f;
            if (valid) {
                float w1 = gg.z - gg.x, h1 = gg.w - gg.y + EPSC;
                ovv = ciou_clip(gg.x, gg.y, gg.z, gg.w, w1 * h1, atanf(w1 / h1), pb, at2);
            }
            if (ovv > best_ov) { best_ov = ovv; best_m = mm; best_valid = valid ? 1 : 0; }
        }
        int lb = (int)gt_labels[b * M + best_m];
        float sc = (best_valid && lb >= 0) ? pd_scores[ba * C + lb] : 0.f;
        float o2 = best_ov * best_ov;
        mm_out = best_m; al = sqrtf(sc) * (o2 * o2 * o2); ov = best_ov;
    }
    claim_m[ba]  = mm_out;
    claim_al[ba] = al;
    atomicMax((unsigned int*)&pos_al[b * M + mm_out], __float_as_uint(al));
    atomicMax((unsigned int*)&pos_ov[b * M + mm_out], __float_as_uint(ov));
}

// K4: fused finalize — per-anchor (bb, fg, nv, lb) then coalesced score writes
__global__ __launch_bounds__(256) void k_final(
    const int* __restrict__ count, const int* __restrict__ claim_m,
    const float* __restrict__ claim_al,
    const float* __restrict__ pos_al, const float* __restrict__ pos_ov,
    const float* __restrict__ gt_labels, const float* __restrict__ gt_bboxes,
    float* __restrict__ out_bb, float* __restrict__ out_ts, float* __restrict__ out_fg,
    int A, int M, int C4, int BA)
{
    __shared__ float s_nv[256];
    __shared__ int   s_lb[256];
    int base_ba = blockIdx.x * 256;
    int tid = threadIdx.x;
    int ba = base_ba + tid;
    if (ba < BA) {
        int b = ba / A;
        int cnt = count[ba];
        int m = claim_m[ba];                   // 0 for background (memset)
        float4 g = reinterpret_cast<const float4*>(gt_bboxes)[b * M + m];
        reinterpret_cast<float4*>(out_bb)[ba] = g;
        float nv = 0.f; int lb = -1;
        if (cnt > 0) {
            lb = max((int)gt_labels[b * M + m], 0);
            nv = claim_al[ba] * pos_ov[b * M + m] / (pos_al[b * M + m] + EPS9);
        }
        out_fg[ba] = (cnt > 0) ? 1.f : 0.f;
        s_nv[tid] = nv; s_lb[tid] = lb;
    } else { s_nv[tid] = 0.f; s_lb[tid] = -1; }
    __syncthreads();
    float4* ts4 = reinterpret_cast<float4*>(out_ts);
    size_t fbase = (size_t)base_ba * C4;
    for (int j = 0; j < C4; ++j) {
        int fl = j * 256 + tid;                // consecutive tid -> consecutive float4s
        int la = fl / C4;
        int ch = fl - la * C4;
        int ba2 = base_ba + la;
        if (ba2 < BA) {
            float nv = s_nv[la];
            int lb = s_lb[la];
            int c0 = ch * 4;
            float4 o;
            o.x = (c0     == lb) ? nv : 0.f;
            o.y = (c0 + 1 == lb) ? nv : 0.f;
            o.z = (c0 + 2 == lb) ? nv : 0.f;
            o.w = (c0 + 3 == lb) ? nv : 0.f;
            ts4[fbase + fl] = o;
        }
    }
}

extern "C" void kernel_launch(void* const* d_in, const int* in_sizes, int n_in,
                              void* d_out, int out_size, void* d_ws, size_t ws_size,
                              hipStream_t stream) {
    const float* pd_scores = (const float*)d_in[0];
    const float* pd_bboxes = (const float*)d_in[1];
    const float* anc       = (const float*)d_in[2];
    const float* gt_labels = (const float*)d_in[3];
    const float* gt_bboxes = (const float*)d_in[4];
    const unsigned char* mask_gt = (const unsigned char*)d_in[5];

    int A  = in_sizes[2] / 2;
    int BA = in_sizes[1] / 4;
    int B  = BA / A;
    int C  = in_sizes[0] / BA;
    int M  = in_sizes[3] / B;
    int BM = B * M;

    // workspace carve (256B-aligned bumps; zeroed span is contiguous)
    char* w = (char*)d_ws;
    auto alloc = [&](size_t bytes) { char* p = w; w += ((bytes + 255) / 256) * 256; return p; };
    int*   mode       = (int*)  alloc(256);
    char*  zero_beg   = w;
    int*   count      = (int*)  alloc((size_t)BA * 4);
    int*   claim_m    = (int*)  alloc((size_t)BA * 4);
    float* pos_al     = (float*)alloc((size_t)BM * 4);
    float* pos_ov     = (float*)alloc((size_t)BM * 4);
    int*   win_fl     = (int*)  alloc((size_t)BM * NTOPK * 4);
    char*  zero_end   = w;
    float* claim_al   = (float*)alloc((size_t)BA * 4);
    int*   win_idx    = (int*)  alloc((size_t)BM * NTOPK * 4);
    float* win_al     = (float*)alloc((size_t)BM * NTOPK * 4);
    int*   cell_start = (int*)  alloc((size_t)(NCELL + 1) * 4);
    int*   binned     = (int*)  alloc((size_t)A * 4);
    float* gp         = (float*)alloc(256);

    float* out_bb = (float*)d_out;
    float* out_ts = out_bb + (size_t)BA * 4;
    float* out_fg = out_ts + (size_t)BA * C;

    hipMemsetAsync(zero_beg, 0, (size_t)(zero_end - zero_beg), stream);

    k_prep<<<1, 1024, 0, stream>>>(mask_gt, BM, mode, anc, A, cell_start, binned, gp);
    k_sel<<<BM, 256, 0, stream>>>(pd_scores, pd_bboxes, anc, gt_labels, gt_bboxes, mask_gt,
                                  mode, cell_start, binned, gp,
                                  count, win_idx, win_al, win_fl, A, C, M, B);
    int nclaims = BM * NTOPK;
    k_resolve<<<(nclaims + 255) / 256, 256, 0, stream>>>(
        pd_scores, pd_bboxes, anc, gt_labels, gt_bboxes, mask_gt, mode,
        count, win_idx, win_al, win_fl, claim_m, claim_al, pos_al, pos_ov, A, C, M, nclaims);
    int C4 = C / 4;
    int gBA = (BA + 255) / 256;
    k_final<<<gBA, 256, 0, stream>>>(count, claim_m, claim_al, pos_al, pos_ov,
                                     gt_labels, gt_bboxes, out_bb, out_ts, out_fg, A, M, C4, BA);
}

// Round 13
// 97.075 us; speedup vs baseline: 1.7906x; 1.0550x over previous
//
#include <hip/hip_runtime.h>
#include <cstdint>
#include <cstddef>

#define EPSC 1e-7f
#define EPS9 1e-9f
#define K4PI2 0.40528473456935108577f
#define NTOPK 10
#define GX 16
#define GY 16
#define NCELL (GX * GY)
#define POOLCAP 2048

__device__ __forceinline__ bool mask_at(const unsigned char* mb, int i, int wide) {
    if (wide) return reinterpret_cast<const unsigned int*>(mb)[i] != 0u;
    return mb[i] != 0;
}

__device__ __forceinline__ unsigned long long shfl_xor_u64(unsigned long long v, int off) {
    int lo = __shfl_xor((int)(unsigned)(v & 0xFFFFFFFFull), off);
    int hi = __shfl_xor((int)(unsigned)(v >> 32), off);
    return ((unsigned long long)(unsigned)hi << 32) | (unsigned)lo;
}

__device__ __forceinline__ unsigned lane_rank(unsigned long long ball) {
    return __builtin_amdgcn_mbcnt_hi((unsigned)(ball >> 32),
           __builtin_amdgcn_mbcnt_lo((unsigned)(ball & 0xFFFFFFFFull), 0u));
}

__device__ __forceinline__ float ciou_clip(float x1a, float y1a, float x2a, float y2a,
                                           float w1h1, float atan1,
                                           float4 pb, float at2) {
    float w2 = pb.z - pb.x, h2 = pb.w - pb.y + EPSC;
    float iw = fmaxf(fminf(x2a, pb.z) - fmaxf(x1a, pb.x), 0.f);
    float ih = fmaxf(fminf(y2a, pb.w) - fmaxf(y1a, pb.y), 0.f);
    float inter = iw * ih;
    float uni = w1h1 + w2 * h2 - inter;
    float iou = inter / (uni + EPSC);
    float cw = fmaxf(x2a, pb.z) - fminf(x1a, pb.x);
    float ch = fmaxf(y2a, pb.w) - fminf(y1a, pb.y);
    float c2 = cw * cw + ch * ch + EPSC;
    float dx = pb.x + pb.z - x1a - x2a;
    float dy = pb.y + pb.w - y1a - y2a;
    float rho2 = (dx * dx + dy * dy) * 0.25f;
    float dat = at2 - atan1;
    float vv = K4PI2 * dat * dat;
    float aa = vv / (vv - iou + (1.f + EPSC));
    return fmaxf(iou - (rho2 / c2 + vv * aa), 0.f);
}

// K0: fused mask-layout detect + spatial binning (single 1024-thread block).
__global__ __launch_bounds__(1024) void k_prep(
    const unsigned char* __restrict__ mask, int nmask, int* __restrict__ mode,
    const float* __restrict__ anc, int A,
    int* __restrict__ cell_start, int* __restrict__ binned, float* __restrict__ gp)
{
    __shared__ int h[NCELL];
    __shared__ int cs[NCELL + 1];
    __shared__ int cur[NCELL];
    __shared__ float rmnx[16], rmny[16], rmxx[16], rmxy[16];
    __shared__ float s_gp[4];
    __shared__ int bad;

    int tid = threadIdx.x;
    int lane = tid & 63, wid = tid >> 6;
    const float2* an2 = reinterpret_cast<const float2*>(anc);

    if (tid == 0) bad = 0;
    if (tid < NCELL) h[tid] = 0;
    __syncthreads();

    const unsigned int* mw = reinterpret_cast<const unsigned int*>(mask);
    int nw = nmask >> 2;
    for (int i = tid; i < nw; i += 1024) {
        unsigned int v = mw[i];
        if (v != 0u && v != 1u && v != 0x3f800000u) atomicOr(&bad, 1);
    }

    float mnx = 3e38f, mny = 3e38f, mxx = -3e38f, mxy = -3e38f;
    for (int i = tid; i < A; i += 1024) {
        float2 p = an2[i];
        mnx = fminf(mnx, p.x); mny = fminf(mny, p.y);
        mxx = fmaxf(mxx, p.x); mxy = fmaxf(mxy, p.y);
    }
#pragma unroll
    for (int off = 32; off; off >>= 1) {
        mnx = fminf(mnx, __shfl_xor(mnx, off));
        mny = fminf(mny, __shfl_xor(mny, off));
        mxx = fmaxf(mxx, __shfl_xor(mxx, off));
        mxy = fmaxf(mxy, __shfl_xor(mxy, off));
    }
    if (lane == 0) { rmnx[wid] = mnx; rmny[wid] = mny; rmxx[wid] = mxx; rmxy[wid] = mxy; }
    __syncthreads();
    if (tid == 0) {
        mode[0] = bad ? 0 : 1;
        float a = 3e38f, b2 = 3e38f, c = -3e38f, d = -3e38f;
        for (int i = 0; i < 16; ++i) {
            a = fminf(a, rmnx[i]); b2 = fminf(b2, rmny[i]);
            c = fmaxf(c, rmxx[i]); d = fmaxf(d, rmxy[i]);
        }
        float rx = fmaxf(c - a, 1e-6f), ry = fmaxf(d - b2, 1e-6f);
        s_gp[0] = a; s_gp[1] = b2;
        s_gp[2] = (float)GX / rx; s_gp[3] = (float)GY / ry;
        gp[0] = s_gp[0]; gp[1] = s_gp[1]; gp[2] = s_gp[2]; gp[3] = s_gp[3];
    }
    __syncthreads();
    float ox = s_gp[0], oy = s_gp[1], ivx = s_gp[2], ivy = s_gp[3];

    for (int i = tid; i < A; i += 1024) {
        float2 p = an2[i];
        int cx = min(GX - 1, max(0, (int)floorf((p.x - ox) * ivx)));
        int cy = min(GY - 1, max(0, (int)floorf((p.y - oy) * ivy)));
        atomicAdd(&h[cy * GX + cx], 1);
    }
    __syncthreads();
    if (wid == 0) {
        int base = 0;
        for (int ch = 0; ch < NCELL / 64; ++ch) {
            int v = h[ch * 64 + lane];
            int inc = v;
            for (int off = 1; off < 64; off <<= 1) {
                int u = __shfl_up(inc, off);
                if (lane >= off) inc += u;
            }
            cs[ch * 64 + lane] = base + inc - v;
            base += __shfl(inc, 63);
        }
        if (lane == 0) cs[NCELL] = base;
    }
    __syncthreads();
    if (tid <= NCELL) cell_start[tid] = cs[tid];
    if (tid < NCELL) cur[tid] = cs[tid];
    __syncthreads();
    for (int i = tid; i < A; i += 1024) {
        float2 p = an2[i];
        int cx = min(GX - 1, max(0, (int)floorf((p.x - ox) * ivx)));
        int cy = min(GY - 1, max(0, (int)floorf((p.y - oy) * ivy)));
        int slot = atomicAdd(&cur[cy * GX + cx], 1);
        binned[slot] = i;
    }
}

#define INTEST(ap) ((ap.x - x1a > EPS9) & (ap.y - y1a > EPS9) & \
                    (x2a - ap.x > EPS9) & (y2a - ap.y > EPS9))

// K2: one 256-thread block per (b,m). Strip-flattened candidate range; 4-wide batched
// gathers; ballot-aggregated LDS pool; single-wave top-10 tournament
// == lax.top_k (value desc, idx asc) via u64 key (val_bits<<32)|~idx.
__global__ __launch_bounds__(256) void k_sel(
    const float* __restrict__ pd_scores, const float* __restrict__ pd_bboxes,
    const float* __restrict__ anc, const float* __restrict__ gt_labels,
    const float* __restrict__ gt_bboxes, const unsigned char* __restrict__ mask_gt,
    const int* __restrict__ mode, const int* __restrict__ cell_start,
    const int* __restrict__ binned, const float* __restrict__ gp,
    int* __restrict__ count, int* __restrict__ win_idx, float* __restrict__ win_al,
    int* __restrict__ win_fl, int* __restrict__ ovf,
    int A, int C, int M, int B)
{
    __shared__ unsigned long long pool[POOLCAP];
    __shared__ int sP[GY + 1];
    __shared__ int sB[GY];
    __shared__ int s_n, s_ovf;

    int bid = blockIdx.x;
    int b = bid % B, m = bid / B;        // XCD swizzle: same-b rows on one XCD (B%8==0)
    int row = b * M + m;
    if (!mask_at(mask_gt, row, mode[0])) return;   // win_fl pre-zeroed -> no claims
    int tid = threadIdx.x;
    int lane = tid & 63, wid = tid >> 6;

    float4 g = reinterpret_cast<const float4*>(gt_bboxes)[row];
    float x1a = g.x, y1a = g.y, x2a = g.z, y2a = g.w;
    float w1 = x2a - x1a, h1 = y2a - y1a + EPSC;
    float w1h1 = w1 * h1;
    float atan1 = atanf(w1 / h1);
    int lbl = (int)gt_labels[row];

    float ox = gp[0], oy = gp[1], ivx = gp[2], ivy = gp[3];
    // identical expressions to k_prep; monotone -> cannot miss any in-box anchor
    int cx0 = min(GX - 1, max(0, (int)floorf((x1a - ox) * ivx)));
    int cx1 = min(GX - 1, max(0, (int)floorf((x2a - ox) * ivx)));
    int cy0 = min(GY - 1, max(0, (int)floorf((y1a - oy) * ivy)));
    int cy1 = min(GY - 1, max(0, (int)floorf((y2a - oy) * ivy)));
    int ns = cy1 - cy0 + 1;

    if (tid == 0) {
        s_n = 0; s_ovf = 0;
        int P = 0;
        for (int s2 = 0; s2 < ns; ++s2) {
            int cbase = (cy0 + s2) * GX;
            int S = cell_start[cbase + cx0];
            int E = cell_start[cbase + cx1 + 1];
            sP[s2] = P; sB[s2] = S - P; P += E - S;
        }
        sP[ns] = P;
    }
    __syncthreads();
    int L = sP[ns];

    const float2* an2 = reinterpret_cast<const float2*>(anc);
    const float4* pb4 = reinterpret_cast<const float4*>(pd_bboxes + (size_t)b * A * 4);
    const float*  ps  = pd_scores + (size_t)b * A * C;

    // Phase A: 4-wide batched candidate processing (static slot names; monotone strip walk)
    int sptr = 0;
    for (int f0 = tid; f0 < L; f0 += 1024) {
        int f1 = f0 + 256, f2 = f0 + 512, f3 = f0 + 768;
        bool o1 = f1 < L, o2 = f2 < L, o3 = f3 < L;
        while (f0 >= sP[sptr + 1]) ++sptr;
        int sl0 = sB[sptr] + f0;
        int sp = sptr;
        if (o1) { while (f1 >= sP[sp + 1]) ++sp; }
        int sl1 = sB[sp] + f1;
        if (o2) { while (f2 >= sP[sp + 1]) ++sp; }
        int sl2 = sB[sp] + f2;
        if (o3) { while (f3 >= sP[sp + 1]) ++sp; }
        int sl3 = sB[sp] + f3;

        int a0 = binned[sl0];
        int a1 = o1 ? binned[sl1] : 0;
        int a2 = o2 ? binned[sl2] : 0;
        int a3 = o3 ? binned[sl3] : 0;
        float2 ap0 = an2[a0], ap1 = an2[a1], ap2 = an2[a2], ap3 = an2[a3];
        bool in0 = INTEST(ap0);
        bool in1 = o1 & INTEST(ap1);
        bool in2 = o2 & INTEST(ap2);
        bool in3 = o3 & INTEST(ap3);

        float4 pb0, pb1, pb2, pb3;
        float sc0 = 0.f, sc1 = 0.f, sc2 = 0.f, sc3 = 0.f;
        if (in0) { pb0 = pb4[a0]; if (lbl >= 0) sc0 = ps[(size_t)a0 * C + lbl]; }
        if (in1) { pb1 = pb4[a1]; if (lbl >= 0) sc1 = ps[(size_t)a1 * C + lbl]; }
        if (in2) { pb2 = pb4[a2]; if (lbl >= 0) sc2 = ps[(size_t)a2 * C + lbl]; }
        if (in3) { pb3 = pb4[a3]; if (lbl >= 0) sc3 = ps[(size_t)a3 * C + lbl]; }

#define PROC(ink, ak, pbk, sck) { \
        unsigned long long key = 0; \
        if (ink) { \
            float w2 = pbk.z - pbk.x, h2 = pbk.w - pbk.y + EPSC; \
            float at2 = atanf(w2 / h2); \
            float ovl = ciou_clip(x1a, y1a, x2a, y2a, w1h1, atan1, pbk, at2); \
            float o2v = ovl * ovl; \
            float val = sqrtf(sck) * (o2v * o2v * o2v); \
            key = ((unsigned long long)__float_as_uint(val) << 32) | (unsigned)(~(unsigned)ak); \
        } \
        unsigned long long ball = __ballot(ink); \
        if (ball) { \
            int bs = 0; \
            if (lane == 0) bs = atomicAdd(&s_n, __popcll(ball)); \
            bs = __shfl(bs, 0); \
            if (ink) { \
                int pos = bs + (int)lane_rank(ball); \
                if (pos < POOLCAP) pool[pos] = key; else s_ovf = 1; \
            } \
        } }
        PROC(in0, a0, pb0, sc0)
        PROC(in1, a1, pb1, sc1)
        PROC(in2, a2, pb2, sc2)
        PROC(in3, a3, pb3, sc3)
#undef PROC
    }
    __syncthreads();
    if (s_ovf || s_n > POOLCAP) {      // never expected for this distribution
        if (tid == 0) ovf[row] = 1;    // exact fallback kernel handles the row
        return;
    }
    if (wid != 0) return;              // Phase B is single-wave, barrier-free

    int n = s_n;
    unsigned long long tv[NTOPK];
#pragma unroll
    for (int j = 0; j < NTOPK; ++j) tv[j] = 0;
    int pcnt = 0;
    for (int i = lane; i < n; i += 64) {
        unsigned long long kk = pool[i];
        pcnt += (kk >> 32) ? 1 : 0;
        if (kk > tv[NTOPK - 1]) {
            tv[NTOPK - 1] = kk;
#pragma unroll
            for (int j = NTOPK - 1; j > 0; --j)
                if (tv[j] > tv[j - 1]) { unsigned long long t = tv[j]; tv[j] = tv[j - 1]; tv[j - 1] = t; }
        }
    }
#pragma unroll
    for (int off = 32; off; off >>= 1) pcnt += __shfl_xor(pcnt, off);
    int p = pcnt;
    int rp = p < NTOPK ? p : NTOPK;
    size_t bA = (size_t)b * A;
    int base_o = row * NTOPK;

    // 3a: positive rounds — register head + wave-max butterfly, winner pops
    for (int k = 0; k < rp; ++k) {
        unsigned long long head = tv[0];
        unsigned long long best = head;
#pragma unroll
        for (int off = 32; off; off >>= 1) {
            unsigned long long o = shfl_xor_u64(best, off);
            if (o > best) best = o;
        }
        if (head == best && head != 0ull) {      // unique owner (keys unique by idx)
            int a = (int)(~(unsigned)(best & 0xFFFFFFFFull));
            int o = base_o + k;
            win_idx[o] = a;
            win_al[o]  = __uint_as_float((unsigned)(best >> 32));
            win_fl[o]  = 1;
            atomicAdd(&count[bA + a], 1);
#pragma unroll
            for (int j = 0; j < NTOPK - 1; ++j) tv[j] = tv[j + 1];
            tv[NTOPK - 1] = 0;
        }
    }

    // 3b (rare: p < 10): fill with smallest-index zero-val anchors; in-box zero-vals
    // (retained in tv: global key-rank of any needed element <= 10 -> lane-rank <= 10) claim.
    if (rp < NTOPK) {
        int iters = (A + 63 - lane) / 64;
        int zp = 0;
        for (int k = rp; k < NTOPK; ++k) {
            unsigned zprop = 0xFFFFFFFFu;        // next out-of-box anchor (padding, no claim)
            while (zp < iters) {
                int a = lane + zp * 64;
                float2 ap = an2[a];
                bool in = INTEST(ap);
                if (!in) { zprop = (unsigned)a; break; }
                ++zp;
            }
            unsigned cprop = 0xFFFFFFFFu;        // unconsumed in-box zero-val (regs)
#pragma unroll
            for (int j = 0; j < NTOPK; ++j) {
                unsigned long long kk = tv[j];
                if (kk != 0ull && kk < (1ull << 32)) {
                    unsigned idx2 = ~(unsigned)kk;
                    if (idx2 < cprop) cprop = idx2;
                }
            }
            unsigned prop = zprop < cprop ? zprop : cprop;
            unsigned bm_ = prop;
#pragma unroll
            for (int off = 32; off; off >>= 1) {
                unsigned o = (unsigned)__shfl_xor((int)bm_, off);
                if (o < bm_) bm_ = o;
            }
            if (bm_ != 0xFFFFFFFFu) {
                if (cprop == bm_ && cprop < zprop) {
                    int o = base_o + k;
                    win_idx[o] = (int)bm_; win_al[o] = 0.f; win_fl[o] = 1;
                    atomicAdd(&count[bA + bm_], 1);
                    unsigned long long wkk = (unsigned long long)(unsigned)(~bm_);
#pragma unroll
                    for (int j = 0; j < NTOPK; ++j) if (tv[j] == wkk) tv[j] = 0;
                } else if (zprop == bm_ && zprop < cprop) {
                    ++zp;
                }
            }
        }
    }
}

// K2fb: exact fallback (r11 single-wave grid-scan) for pool-overflow rows only
__global__ __launch_bounds__(64) void k_sel_fb(
    const float* __restrict__ pd_scores, const float* __restrict__ pd_bboxes,
    const float* __restrict__ anc, const float* __restrict__ gt_labels,
    const float* __restrict__ gt_bboxes, const unsigned char* __restrict__ mask_gt,
    const int* __restrict__ mode, const int* __restrict__ cell_start,
    const int* __restrict__ binned, const float* __restrict__ gp,
    const int* __restrict__ ovf,
    int* __restrict__ count, int* __restrict__ win_idx, float* __restrict__ win_al,
    int* __restrict__ win_fl,
    int A, int C, int M)
{
    int row = blockIdx.x;
    if (!ovf[row]) return;
    if (!mask_at(mask_gt, row, mode[0])) return;
    int b = row / M;
    int lane = threadIdx.x;

    float4 g = reinterpret_cast<const float4*>(gt_bboxes)[row];
    float x1a = g.x, y1a = g.y, x2a = g.z, y2a = g.w;
    float w1 = x2a - x1a, h1 = y2a - y1a + EPSC;
    float w1h1 = w1 * h1;
    float atan1 = atanf(w1 / h1);
    int lbl = (int)gt_labels[row];

    float ox = gp[0], oy = gp[1], ivx = gp[2], ivy = gp[3];
    int cx0 = min(GX - 1, max(0, (int)floorf((x1a - ox) * ivx)));
    int cx1 = min(GX - 1, max(0, (int)floorf((x2a - ox) * ivx)));
    int cy0 = min(GY - 1, max(0, (int)floorf((y1a - oy) * ivy)));
    int cy1 = min(GY - 1, max(0, (int)floorf((y2a - oy) * ivy)));

    const float2* an2 = reinterpret_cast<const float2*>(anc);
    const float4* pb4 = reinterpret_cast<const float4*>(pd_bboxes + (size_t)b * A * 4);
    const float*  ps  = pd_scores + (size_t)b * A * C;

    unsigned long long tv[NTOPK];
#pragma unroll
    for (int j = 0; j < NTOPK; ++j) tv[j] = 0;
    int pcnt = 0;

    for (int cy = cy0; cy <= cy1; ++cy) {
        int c0 = cy * GX + cx0;
        int s = cell_start[c0], e = cell_start[cy * GX + cx1 + 1];
        for (int i = s + lane; i < e; i += 64) {
            int a = binned[i];
            float2 ap = an2[a];
            bool in = INTEST(ap);
            if (in) {
                float4 pb = pb4[a];
                float w2 = pb.z - pb.x, h2 = pb.w - pb.y + EPSC;
                float at2 = atanf(w2 / h2);
                float ovl = ciou_clip(x1a, y1a, x2a, y2a, w1h1, atan1, pb, at2);
                float sc = (lbl >= 0) ? ps[(size_t)a * C + lbl] : 0.f;
                float o2 = ovl * ovl;
                float val = sqrtf(sc) * (o2 * o2 * o2);
                pcnt += (val > 0.f) ? 1 : 0;
                unsigned long long kk =
                    ((unsigned long long)__float_as_uint(val) << 32) | (unsigned)(~(unsigned)a);
                if (kk > tv[NTOPK - 1]) {
                    tv[NTOPK - 1] = kk;
#pragma unroll
                    for (int j = NTOPK - 1; j > 0; --j)
                        if (tv[j] > tv[j - 1]) {
                            unsigned long long t = tv[j]; tv[j] = tv[j - 1]; tv[j - 1] = t;
                        }
                }
            }
        }
    }

#pragma unroll
    for (int off = 32; off; off >>= 1) pcnt += __shfl_xor(pcnt, off);
    int p = pcnt;
    int rp = p < NTOPK ? p : NTOPK;
    size_t bA = (size_t)b * A;
    int base_o = row * NTOPK;

    for (int k = 0; k < rp; ++k) {
        unsigned long long head = tv[0];
        unsigned long long best = head;
#pragma unroll
        for (int off = 32; off; off >>= 1) {
            unsigned long long o = shfl_xor_u64(best, off);
            if (o > best) best = o;
        }
        if (head == best && head != 0ull) {
            int a = (int)(~(unsigned)(best & 0xFFFFFFFFull));
            int o = base_o + k;
            win_idx[o] = a;
            win_al[o]  = __uint_as_float((unsigned)(best >> 32));
            win_fl[o]  = 1;
            atomicAdd(&count[bA + a], 1);
#pragma unroll
            for (int j = 0; j < NTOPK - 1; ++j) tv[j] = tv[j + 1];
            tv[NTOPK - 1] = 0;
        }
    }

    if (rp < NTOPK) {
        int iters = (A + 63 - lane) / 64;
        int zp = 0;
        for (int k = rp; k < NTOPK; ++k) {
            unsigned zprop = 0xFFFFFFFFu;
            while (zp < iters) {
                int a = lane + zp * 64;
                float2 ap = an2[a];
                bool in = INTEST(ap);
                if (!in) { zprop = (unsigned)a; break; }
                ++zp;
            }
            unsigned cprop = 0xFFFFFFFFu;
#pragma unroll
            for (int j = 0; j < NTOPK; ++j) {
                unsigned long long kk = tv[j];
                if (kk != 0ull && kk < (1ull << 32)) {
                    unsigned idx2 = ~(unsigned)kk;
                    if (idx2 < cprop) cprop = idx2;
                }
            }
            unsigned prop = zprop < cprop ? zprop : cprop;
            unsigned bm_ = prop;
#pragma unroll
            for (int off = 32; off; off >>= 1) {
                unsigned o = (unsigned)__shfl_xor((int)bm_, off);
                if (o < bm_) bm_ = o;
            }
            if (bm_ != 0xFFFFFFFFu) {
                if (cprop == bm_ && cprop < zprop) {
                    int o = base_o + k;
                    win_idx[o] = (int)bm_; win_al[o] = 0.f; win_fl[o] = 1;
                    atomicAdd(&count[bA + bm_], 1);
                    unsigned long long wkk = (unsigned long long)(unsigned)(~bm_);
#pragma unroll
                    for (int j = 0; j < NTOPK; ++j) if (tv[j] == wkk) tv[j] = 0;
                } else if (zprop == bm_ && zprop < cprop) {
                    ++zp;
                }
            }
        }
    }
}

// K3: claim resolution + fused pos_al/pos_ov atomicMax (winner CIoU recomputed)
__global__ void k_resolve(
    const float* __restrict__ pd_scores, const float* __restrict__ pd_bboxes,
    const float* __restrict__ anc, const float* __restrict__ gt_labels,
    const float* __restrict__ gt_bboxes, const unsigned char* __restrict__ mask_gt,
    const int* __restrict__ mode,
    const int* __restrict__ count, const int* __restrict__ win_idx,
    const float* __restrict__ win_al, const int* __restrict__ win_fl,
    int* __restrict__ claim_m, float* __restrict__ claim_al,
    float* __restrict__ pos_al, float* __restrict__ pos_ov,
    int A, int C, int M, int total)
{
    int t = blockIdx.x * 256 + threadIdx.x;
    if (t >= total) return;
    int bm = t / NTOPK;
    int b = bm / M, m = bm % M;
    if (!win_fl[t]) return;
    int a = win_idx[t];
    size_t ba = (size_t)b * A + a;
    int cnt = count[ba];
    float al, ov; int mm_out;
    if (cnt == 1) {
        mm_out = m; al = win_al[t];
        float4 gg = reinterpret_cast<const float4*>(gt_bboxes)[b * M + m];
        float w1 = gg.z - gg.x, h1 = gg.w - gg.y + EPSC;
        float4 pb = reinterpret_cast<const float4*>(pd_bboxes)[ba];
        float w2 = pb.z - pb.x, h2p = pb.w - pb.y + EPSC;
        ov = ciou_clip(gg.x, gg.y, gg.z, gg.w, w1 * h1, atanf(w1 / h1), pb, atanf(w2 / h2p));
    } else {
        int wide = mode[0];
        float4 pb = reinterpret_cast<const float4*>(pd_bboxes)[ba];
        float2 ap = reinterpret_cast<const float2*>(anc)[a];
        float w2 = pb.z - pb.x, h2p = pb.w - pb.y + EPSC;
        float at2 = atanf(w2 / h2p);
        float best_ov = -1.f; int best_m = 0, best_valid = 0;
        for (int mm = 0; mm < M; ++mm) {
            float4 gg = reinterpret_cast<const float4*>(gt_bboxes)[b * M + mm];
            bool in = (ap.x - gg.x > EPS9) && (ap.y - gg.y > EPS9) &&
                      (gg.z - ap.x > EPS9) && (gg.w - ap.y > EPS9);
            bool valid = in && mask_at(mask_gt, b * M + mm, wide);
            float ovv = 0.f;
            if (valid) {
                float w1 = gg.z - gg.x, h1 = gg.w - gg.y + EPSC;
                ovv = ciou_clip(gg.x, gg.y, gg.z, gg.w, w1 * h1, atanf(w1 / h1), pb, at2);
            }
            if (ovv > best_ov) { best_ov = ovv; best_m = mm; best_valid = valid ? 1 : 0; }
        }
        int lb = (int)gt_labels[b * M + best_m];
        float sc = (best_valid && lb >= 0) ? pd_scores[ba * C + lb] : 0.f;
        float o2 = best_ov * best_ov;
        mm_out = best_m; al = sqrtf(sc) * (o2 * o2 * o2); ov = best_ov;
    }
    claim_m[ba]  = mm_out;
    claim_al[ba] = al;
    atomicMax((unsigned int*)&pos_al[b * M + mm_out], __float_as_uint(al));
    atomicMax((unsigned int*)&pos_ov[b * M + mm_out], __float_as_uint(ov));
}

// K4: fused finalize — per-anchor (bb, fg, nv, lb) then coalesced score writes
__global__ __launch_bounds__(256) void k_final(
    const int* __restrict__ count, const int* __restrict__ claim_m,
    const float* __restrict__ claim_al,
    const float* __restrict__ pos_al, const float* __restrict__ pos_ov,
    const float* __restrict__ gt_labels, const float* __restrict__ gt_bboxes,
    float* __restrict__ out_bb, float* __restrict__ out_ts, float* __restrict__ out_fg,
    int A, int M, int C4, int BA)
{
    __shared__ float s_nv[256];
    __shared__ int   s_lb[256];
    int base_ba = blockIdx.x * 256;
    int tid = threadIdx.x;
    int ba = base_ba + tid;
    if (ba < BA) {
        int b = ba / A;
        int cnt = count[ba];
        int m = claim_m[ba];                   // 0 for background (memset)
        float4 g = reinterpret_cast<const float4*>(gt_bboxes)[b * M + m];
        reinterpret_cast<float4*>(out_bb)[ba] = g;
        float nv = 0.f; int lb = -1;
        if (cnt > 0) {
            lb = max((int)gt_labels[b * M + m], 0);
            nv = claim_al[ba] * pos_ov[b * M + m] / (pos_al[b * M + m] + EPS9);
        }
        out_fg[ba] = (cnt > 0) ? 1.f : 0.f;
        s_nv[tid] = nv; s_lb[tid] = lb;
    } else { s_nv[tid] = 0.f; s_lb[tid] = -1; }
    __syncthreads();
    float4* ts4 = reinterpret_cast<float4*>(out_ts);
    size_t fbase = (size_t)base_ba * C4;
    for (int j = 0; j < C4; ++j) {
        int fl = j * 256 + tid;                // consecutive tid -> consecutive float4s
        int la = fl / C4;
        int ch = fl - la * C4;
        int ba2 = base_ba + la;
        if (ba2 < BA) {
            float nv = s_nv[la];
            int lb = s_lb[la];
            int c0 = ch * 4;
            float4 o;
            o.x = (c0     == lb) ? nv : 0.f;
            o.y = (c0 + 1 == lb) ? nv : 0.f;
            o.z = (c0 + 2 == lb) ? nv : 0.f;
            o.w = (c0 + 3 == lb) ? nv : 0.f;
            ts4[fbase + fl] = o;
        }
    }
}

extern "C" void kernel_launch(void* const* d_in, const int* in_sizes, int n_in,
                              void* d_out, int out_size, void* d_ws, size_t ws_size,
                              hipStream_t stream) {
    const float* pd_scores = (const float*)d_in[0];
    const float* pd_bboxes = (const float*)d_in[1];
    const float* anc       = (const float*)d_in[2];
    const float* gt_labels = (const float*)d_in[3];
    const float* gt_bboxes = (const float*)d_in[4];
    const unsigned char* mask_gt = (const unsigned char*)d_in[5];

    int A  = in_sizes[2] / 2;
    int BA = in_sizes[1] / 4;
    int B  = BA / A;
    int C  = in_sizes[0] / BA;
    int M  = in_sizes[3] / B;
    int BM = B * M;

    // workspace carve (256B-aligned bumps; zeroed span is contiguous)
    char* w = (char*)d_ws;
    auto alloc = [&](size_t bytes) { char* p = w; w += ((bytes + 255) / 256) * 256; return p; };
    int*   mode       = (int*)  alloc(256);
    char*  zero_beg   = w;
    int*   count      = (int*)  alloc((size_t)BA * 4);
    int*   claim_m    = (int*)  alloc((size_t)BA * 4);
    float* pos_al     = (float*)alloc((size_t)BM * 4);
    float* pos_ov     = (float*)alloc((size_t)BM * 4);
    int*   win_fl     = (int*)  alloc((size_t)BM * NTOPK * 4);
    int*   ovf        = (int*)  alloc((size_t)BM * 4);
    char*  zero_end   = w;
    float* claim_al   = (float*)alloc((size_t)BA * 4);
    int*   win_idx    = (int*)  alloc((size_t)BM * NTOPK * 4);
    float* win_al     = (float*)alloc((size_t)BM * NTOPK * 4);
    int*   cell_start = (int*)  alloc((size_t)(NCELL + 1) * 4);
    int*   binned     = (int*)  alloc((size_t)A * 4);
    float* gp         = (float*)alloc(256);

    float* out_bb = (float*)d_out;
    float* out_ts = out_bb + (size_t)BA * 4;
    float* out_fg = out_ts + (size_t)BA * C;

    hipMemsetAsync(zero_beg, 0, (size_t)(zero_end - zero_beg), stream);

    k_prep<<<1, 1024, 0, stream>>>(mask_gt, BM, mode, anc, A, cell_start, binned, gp);
    k_sel<<<BM, 256, 0, stream>>>(pd_scores, pd_bboxes, anc, gt_labels, gt_bboxes, mask_gt,
                                  mode, cell_start, binned, gp,
                                  count, win_idx, win_al, win_fl, ovf, A, C, M, B);
    k_sel_fb<<<BM, 64, 0, stream>>>(pd_scores, pd_bboxes, anc, gt_labels, gt_bboxes, mask_gt,
                                    mode, cell_start, binned, gp, ovf,
                                    count, win_idx, win_al, win_fl, A, C, M);
    int nclaims = BM * NTOPK;
    k_resolve<<<(nclaims + 255) / 256, 256, 0, stream>>>(
        pd_scores, pd_bboxes, anc, gt_labels, gt_bboxes, mask_gt, mode,
        count, win_idx, win_al, win_fl, claim_m, claim_al, pos_al, pos_ov, A, C, M, nclaims);
    int C4 = C / 4;
    int gBA = (BA + 255) / 256;
    k_final<<<gBA, 256, 0, stream>>>(count, claim_m, claim_al, pos_al, pos_ov,
                                     gt_labels, gt_bboxes, out_bb, out_ts, out_fg, A, M, C4, BA);
}